// Round 1
// baseline (322.275 us; speedup 1.0000x reference)
//
#include <hip/hip_runtime.h>
#include <cstddef>

#define BH_ 16
#define N_  2048
#define D_  64
#define M_  256
#define C_  64
#define NC_ 32   // N_/C_

// monotone float<->uint encoding for atomicMax on floats (handles negatives)
__device__ __forceinline__ unsigned enc_f(float f) {
  unsigned u = __float_as_uint(f);
  return (u & 0x80000000u) ? ~u : (u | 0x80000000u);
}
__device__ __forceinline__ float dec_f(unsigned e) {
  unsigned u = (e & 0x80000000u) ? (e & 0x7FFFFFFFu) : ~e;
  return __uint_as_float(u);
}

__global__ void init_kernel(unsigned* kmaxE) {
  if (threadIdx.x < BH_) kmaxE[threadIdx.x] = 0u;  // encodes "most negative"
}

// MODE 0: q-features (per-row max). MODE 1: k global-max pass. MODE 2: k-features.
// Each block: 64 consecutive rows (global row = bh*N + n), 256 threads, thread t owns feature m=t.
// proj row m is preloaded into 64 VGPRs (scaled by normalizer); q-row loads are wave-uniform -> s_load.
template <int MODE>
__global__ __launch_bounds__(256) void feat_kernel(
    const float* __restrict__ x, const float* __restrict__ proj,
    float* __restrict__ outp, unsigned* __restrict__ kmaxE)
{
  const int t = threadIdx.x;
  const int row0 = blockIdx.x * 64;
  const float NRM = 0.35355339059327373f;  // 64^-0.25

  float p[64];
  {
    const float4* pr = (const float4*)(proj + (size_t)t * 64);
#pragma unroll
    for (int i = 0; i < 16; ++i) {
      float4 f = pr[i];
      p[4*i+0] = NRM * f.x; p[4*i+1] = NRM * f.y;
      p[4*i+2] = NRM * f.z; p[4*i+3] = NRM * f.w;
    }
  }

  __shared__ float diagS[64];
  __shared__ float wred[2][4];
  __shared__ float wmaxS[4];

  if (MODE != 1) {
    // diag[r] = 0.5*nrm^2*sum(q^2) = 0.0625*sum(q_raw^2)
    int r = t >> 2, q4 = t & 3;
    const float4* qr = (const float4*)(x + (size_t)(row0 + r) * 64 + q4 * 16);
    float s = 0.f;
#pragma unroll
    for (int i = 0; i < 4; ++i) { float4 f = qr[i]; s += f.x*f.x + f.y*f.y + f.z*f.z + f.w*f.w; }
    s += __shfl_xor(s, 1); s += __shfl_xor(s, 2);
    if (q4 == 0) diagS[r] = 0.0625f * s;
  }
  float mxbh = 0.f;
  if (MODE == 2) mxbh = dec_f(kmaxE[row0 / N_]);
  __syncthreads();

  float runmax = -3.4e38f;
  for (int r = 0; r < 64; ++r) {
    const float* xrow = x + (size_t)(row0 + r) * 64;  // uniform address
    float acc = 0.f;
#pragma unroll
    for (int d = 0; d < 64; ++d) acc = fmaf(xrow[d], p[d], acc);

    if (MODE == 1) { runmax = fmaxf(runmax, acc); continue; }

    float val;
    if (MODE == 0) {
      float mx = acc;
#pragma unroll
      for (int off = 1; off < 64; off <<= 1) mx = fmaxf(mx, __shfl_xor(mx, off));
      if ((t & 63) == 0) wred[r & 1][t >> 6] = mx;
      __syncthreads();
      float bm = fmaxf(fmaxf(wred[r & 1][0], wred[r & 1][1]),
                       fmaxf(wred[r & 1][2], wred[r & 1][3]));
      val = 0.0625f * (__expf(acc - diagS[r] - bm) + 1e-4f);
    } else {
      val = 0.0625f * (__expf(acc - diagS[r] - mxbh) + 1e-4f);
    }
    outp[(size_t)(row0 + r) * M_ + t] = val;
  }

  if (MODE == 1) {
#pragma unroll
    for (int off = 1; off < 64; off <<= 1) runmax = fmaxf(runmax, __shfl_xor(runmax, off));
    if ((t & 63) == 0) wmaxS[t >> 6] = runmax;
    __syncthreads();
    if (t == 0) {
      float m = fmaxf(fmaxf(wmaxS[0], wmaxS[1]), fmaxf(wmaxS[2], wmaxS[3]));
      atomicMax(kmaxE + (row0 / N_), enc_f(m));
    }
  }
}

// Per-chunk sums: ksum[m] = sum_s k'[s][m]; kv[m][d] = sum_s k'[s][m]*v[s][d].
// Block = one chunk (64 rows), thread t owns m=t, kv row in 64 VGPRs. v rows are uniform -> s_load.
__global__ __launch_bounds__(256) void chunksum_kernel(
    const float* __restrict__ kp, const float* __restrict__ v,
    float* __restrict__ ksum, float* __restrict__ kv)
{
  const int t = threadIdx.x;
  const int blk = blockIdx.x;       // bh*NC + ch
  const int row0 = blk * C_;
  float acc[64];
#pragma unroll
  for (int d = 0; d < 64; ++d) acc[d] = 0.f;
  float ks = 0.f;
  for (int s = 0; s < C_; ++s) {
    float kval = kp[(size_t)(row0 + s) * M_ + t];
    ks += kval;
    const float* vr = v + (size_t)(row0 + s) * D_;  // uniform
#pragma unroll
    for (int d = 0; d < 64; ++d) acc[d] = fmaf(kval, vr[d], acc[d]);
  }
  ksum[(size_t)blk * M_ + t] = ks;
  float* kvo = kv + ((size_t)blk * M_ + t) * D_;
#pragma unroll
  for (int d = 0; d < 64; d += 4)
    *(float4*)(kvo + d) = make_float4(acc[d], acc[d+1], acc[d+2], acc[d+3]);
}

// Exclusive prefix over chunks, in place. Grid = BH*64; block handles 256 of the 16384 kv elems.
__global__ __launch_bounds__(256) void scan_kernel(float* __restrict__ ksum, float* __restrict__ kv)
{
  const int t = threadIdx.x;
  const int bh = blockIdx.x >> 6;
  const int sl = blockIdx.x & 63;
  {
    size_t base = (size_t)bh * NC_ * M_ * D_ + (size_t)sl * 256 + t;
    float carry = 0.f;
    for (int ch = 0; ch < NC_; ++ch) {
      float* ptr = kv + base + (size_t)ch * (M_ * D_);
      float xv = *ptr; *ptr = carry; carry += xv;
    }
  }
  if (sl == 0) {
    size_t base = (size_t)bh * NC_ * M_ + t;
    float carry = 0.f;
    for (int ch = 0; ch < NC_; ++ch) {
      float* ptr = ksum + base + (size_t)ch * M_;
      float xv = *ptr; *ptr = carry; carry += xv;
    }
  }
}

// Per chunk: O = Q'.S_prev + tril(Q'K'^T).V ; den = Q'.ksum_prev + rowsum(tril(A)) + 1e-6*sum(Q').
// Block = one chunk (64 rows), 256 threads, 4x4 micro-tile per thread, m-tiled by 64 through LDS.
__global__ __launch_bounds__(256) void out_kernel(
    const float* __restrict__ qp, const float* __restrict__ kp,
    const float* __restrict__ v, const float* __restrict__ ksE_g,
    const float* __restrict__ kvE_g, float* __restrict__ out)
{
  const int t = threadIdx.x;
  const int blk = blockIdx.x;       // bh*NC + ch
  const int row0 = blk * C_;
  const int ti = t >> 4, tj = t & 15;

  __shared__ float lds[3 * 64 * 68];
  float (*qpT)[68] = (float (*)[68])lds;                 // [j][r]
  float (*kpT)[68] = (float (*)[68])(lds + 64 * 68);     // [j][s]
  float (*SpS)[68] = (float (*)[68])(lds + 2 * 64 * 68); // [j][d]
  float (*AmT)[68] = qpT;                                // phase 2: [s][r]
  float (*vS)[68]  = kpT;                                // phase 2: [s][d]
  __shared__ float ksE[64];
  __shared__ float denS[64];

  float A[4][4] = {}, O[4][4] = {};
  float den4[4] = {}, qs4[4] = {};
  const int r = t >> 2, q4 = t & 3;

  for (int mt = 0; mt < 4; ++mt) {
    __syncthreads();
#pragma unroll
    for (int i = 0; i < 4; ++i) {
      int mo = q4 * 16 + i * 4;
      float4 f = *(const float4*)(qp + (size_t)(row0 + r) * M_ + mt * 64 + mo);
      qpT[mo+0][r] = f.x; qpT[mo+1][r] = f.y; qpT[mo+2][r] = f.z; qpT[mo+3][r] = f.w;
      float4 g = *(const float4*)(kp + (size_t)(row0 + r) * M_ + mt * 64 + mo);
      kpT[mo+0][r] = g.x; kpT[mo+1][r] = g.y; kpT[mo+2][r] = g.z; kpT[mo+3][r] = g.w;
      float4 h = *(const float4*)(kvE_g + ((size_t)blk * M_ + mt * 64 + r) * D_ + mo);
      *(float4*)&SpS[r][mo] = h;
    }
    if (t < 64) ksE[t] = ksE_g[(size_t)blk * M_ + mt * 64 + t];
    __syncthreads();

    for (int j = 0; j < 64; ++j) {
      float4 qv = *(const float4*)&qpT[j][ti * 4];
      float4 kq = *(const float4*)&kpT[j][tj * 4];
      float4 sv = *(const float4*)&SpS[j][tj * 4];
      float ksj = ksE[j];
      float qa[4] = {qv.x, qv.y, qv.z, qv.w};
      float kb[4] = {kq.x, kq.y, kq.z, kq.w};
      float sb[4] = {sv.x, sv.y, sv.z, sv.w};
#pragma unroll
      for (int a = 0; a < 4; ++a) {
#pragma unroll
        for (int b = 0; b < 4; ++b) {
          A[a][b] = fmaf(qa[a], kb[b], A[a][b]);
          O[a][b] = fmaf(qa[a], sb[b], O[a][b]);
        }
        den4[a] = fmaf(qa[a], ksj, den4[a]);
        qs4[a] += qa[a];
      }
    }
  }
  __syncthreads();  // phase-1 LDS reads done; safe to overwrite aliased regions

  // causal mask, write A^T to LDS, accumulate den_intra
  float dintra[4] = {};
#pragma unroll
  for (int a = 0; a < 4; ++a) {
    int ri = ti * 4 + a;
#pragma unroll
    for (int b = 0; b < 4; ++b) {
      int sj = tj * 4 + b;
      float av = (sj <= ri) ? A[a][b] : 0.f;
      AmT[sj][ri] = av;
      dintra[a] += av;
    }
  }
#pragma unroll
  for (int off = 1; off < 16; off <<= 1) {
#pragma unroll
    for (int a = 0; a < 4; ++a) dintra[a] += __shfl_xor(dintra[a], off);
  }
#pragma unroll
  for (int i = 0; i < 4; ++i) {   // stage v chunk
    int mo = q4 * 16 + i * 4;
    float4 f = *(const float4*)(v + (size_t)(row0 + r) * D_ + mo);
    *(float4*)&vS[r][mo] = f;
  }
  if (tj == 0) {
#pragma unroll
    for (int a = 0; a < 4; ++a)
      denS[ti * 4 + a] = den4[a] + dintra[a] + 1e-6f * qs4[a];
  }
  __syncthreads();

  for (int s = 0; s < 64; ++s) {
    float4 a4 = *(const float4*)&AmT[s][ti * 4];
    float4 vv = *(const float4*)&vS[s][tj * 4];
    float aa[4] = {a4.x, a4.y, a4.z, a4.w};
    float vb[4] = {vv.x, vv.y, vv.z, vv.w};
#pragma unroll
    for (int a = 0; a < 4; ++a)
#pragma unroll
      for (int b = 0; b < 4; ++b)
        O[a][b] = fmaf(aa[a], vb[b], O[a][b]);
  }

#pragma unroll
  for (int a = 0; a < 4; ++a) {
    float dinv = 1.f / denS[ti * 4 + a];
    float4 o4 = make_float4(O[a][0] * dinv, O[a][1] * dinv, O[a][2] * dinv, O[a][3] * dinv);
    *(float4*)(out + (size_t)(row0 + ti * 4 + a) * D_ + tj * 4) = o4;
  }
}

extern "C" void kernel_launch(void* const* d_in, const int* in_sizes, int n_in,
                              void* d_out, int out_size, void* d_ws, size_t ws_size,
                              hipStream_t stream)
{
  (void)in_sizes; (void)n_in; (void)out_size; (void)ws_size;
  const float* q    = (const float*)d_in[0];
  const float* k    = (const float*)d_in[1];
  const float* v    = (const float*)d_in[2];
  const float* proj = (const float*)d_in[3];
  float* out = (float*)d_out;

  float* ws = (float*)d_ws;
  const size_t SQP = (size_t)BH_ * N_ * M_;                 // 8,388,608 floats
  float* qp   = ws;
  float* kp   = ws + SQP;
  float* ksum = ws + 2 * SQP;                               // BH*NC*M = 131072
  float* kv   = ksum + (size_t)BH_ * NC_ * M_;              // BH*NC*M*D = 8,388,608
  unsigned* kmaxE = (unsigned*)(kv + (size_t)BH_ * NC_ * M_ * D_);
  // total ws use: ~96.5 MiB

  init_kernel<<<dim3(1), dim3(64), 0, stream>>>(kmaxE);
  feat_kernel<0><<<dim3(BH_ * N_ / 64), dim3(256), 0, stream>>>(q, proj, qp, kmaxE);
  feat_kernel<1><<<dim3(BH_ * N_ / 64), dim3(256), 0, stream>>>(k, proj, kp, kmaxE);
  feat_kernel<2><<<dim3(BH_ * N_ / 64), dim3(256), 0, stream>>>(k, proj, kp, kmaxE);
  chunksum_kernel<<<dim3(BH_ * NC_), dim3(256), 0, stream>>>(kp, v, ksum, kv);
  scan_kernel<<<dim3(BH_ * 64), dim3(256), 0, stream>>>(ksum, kv);
  out_kernel<<<dim3(BH_ * NC_), dim3(256), 0, stream>>>(qp, kp, v, ksum, kv, out);
}

// Round 2
// 206.539 us; speedup vs baseline: 1.5604x; 1.5604x over previous
//
#include <hip/hip_runtime.h>
#include <cstddef>

#define BH_ 16
#define N_  2048
#define D_  64
#define M_  256
#define C_  64
#define NC_ 32   // N_/C_

// monotone float<->uint encoding for atomicMax on floats (handles negatives)
__device__ __forceinline__ unsigned enc_f(float f) {
  unsigned u = __float_as_uint(f);
  return (u & 0x80000000u) ? ~u : (u | 0x80000000u);
}
__device__ __forceinline__ float dec_f(unsigned e) {
  unsigned u = (e & 0x80000000u) ? (e & 0x7FFFFFFFu) : ~e;
  return __uint_as_float(u);
}

__global__ void init_kernel(unsigned* kmaxE) {
  if (threadIdx.x < BH_) kmaxE[threadIdx.x] = 0u;  // encodes "most negative"
}

// Register-tiled feature GEMM: out tile 64 rows x 256 cols per block, 512 threads,
// 4x8 microtile (rows ti*4+a, cols h*128+tj*4+b). x staged transposed+scaled in LDS,
// proj staged transposed per 128-col half.
// ISQ=0: write raw xd, atomicMax per-bh global max. ISQ=1: per-row max, exp, write q'.
template <int ISQ>
__global__ __launch_bounds__(512, 4) void gemm_feat(
    const float* __restrict__ x, const float* __restrict__ proj,
    float* __restrict__ outp, unsigned* __restrict__ kmaxE)
{
  const int t = threadIdx.x;
  const int row0 = blockIdx.x * 64;
  const int ti = t >> 5;   // 0..15
  const int tj = t & 31;   // 0..31
  const float NRM = 0.35355339059327373f;  // 64^-0.25

  __shared__ float xT[64][68];    // [k][row], scaled by NRM
  __shared__ float pT[64][132];   // [k][m-within-half]
  __shared__ float diagS[64];
  __shared__ float wmaxS[8];

  {  // stage xT: thread covers row r, cols oct*8..+7
    int r = t >> 3, oct = t & 7;
    const float4* src = (const float4*)(x + (size_t)(row0 + r) * 64 + oct * 8);
    float4 f0 = src[0], f1 = src[1];
    xT[oct*8+0][r] = NRM*f0.x; xT[oct*8+1][r] = NRM*f0.y;
    xT[oct*8+2][r] = NRM*f0.z; xT[oct*8+3][r] = NRM*f0.w;
    xT[oct*8+4][r] = NRM*f1.x; xT[oct*8+5][r] = NRM*f1.y;
    xT[oct*8+6][r] = NRM*f1.z; xT[oct*8+7][r] = NRM*f1.w;
  }
  __syncthreads();
  if (ISQ && t < 64) {
    float s = 0.f;
#pragma unroll 16
    for (int kk = 0; kk < 64; ++kk) { float vv = xT[kk][t]; s = fmaf(vv, vv, s); }
    diagS[t] = 0.5f * s;   // xT already scaled: 0.5*nrm^2*sum(x^2)
  }

  float A[4][8];
#pragma unroll
  for (int a = 0; a < 4; ++a)
#pragma unroll
    for (int b = 0; b < 8; ++b) A[a][b] = 0.f;

  for (int h = 0; h < 2; ++h) {
    __syncthreads();
    {  // stage pT half: thread covers m, k-range q4*16..+15
      int m = t >> 2, q4 = t & 3;
      const float4* src = (const float4*)(proj + (size_t)(h*128 + m) * 64 + q4 * 16);
#pragma unroll
      for (int i = 0; i < 4; ++i) {
        float4 f = src[i];
        pT[q4*16+i*4+0][m] = f.x; pT[q4*16+i*4+1][m] = f.y;
        pT[q4*16+i*4+2][m] = f.z; pT[q4*16+i*4+3][m] = f.w;
      }
    }
    __syncthreads();
#pragma unroll 4
    for (int kk = 0; kk < 64; ++kk) {
      float4 x4 = *(const float4*)&xT[kk][ti*4];
      float4 p4 = *(const float4*)&pT[kk][tj*4];
      float xr[4] = {x4.x, x4.y, x4.z, x4.w};
      float pc[4] = {p4.x, p4.y, p4.z, p4.w};
#pragma unroll
      for (int a = 0; a < 4; ++a)
#pragma unroll
        for (int b = 0; b < 4; ++b)
          A[a][h*4+b] = fmaf(xr[a], pc[b], A[a][h*4+b]);
    }
  }

  if (!ISQ) {
    float mx = A[0][0];
#pragma unroll
    for (int a = 0; a < 4; ++a)
#pragma unroll
      for (int b = 0; b < 8; ++b) mx = fmaxf(mx, A[a][b]);
#pragma unroll
    for (int off = 1; off < 64; off <<= 1) mx = fmaxf(mx, __shfl_xor(mx, off));
    if ((t & 63) == 0) wmaxS[t >> 6] = mx;
    __syncthreads();
    if (t == 0) {
      float m = wmaxS[0];
#pragma unroll
      for (int w = 1; w < 8; ++w) m = fmaxf(m, wmaxS[w]);
      atomicMax(kmaxE + (row0 / N_), enc_f(m));
    }
#pragma unroll
    for (int a = 0; a < 4; ++a)
#pragma unroll
      for (int h = 0; h < 2; ++h)
        *(float4*)(outp + (size_t)(row0 + ti*4 + a) * M_ + h*128 + tj*4) =
            make_float4(A[a][h*4+0], A[a][h*4+1], A[a][h*4+2], A[a][h*4+3]);
  } else {
#pragma unroll
    for (int a = 0; a < 4; ++a) {
      float mx = A[a][0];
#pragma unroll
      for (int b = 1; b < 8; ++b) mx = fmaxf(mx, A[a][b]);
#pragma unroll
      for (int off = 1; off < 32; off <<= 1) mx = fmaxf(mx, __shfl_xor(mx, off));
      float dg = diagS[ti*4 + a];
#pragma unroll
      for (int h = 0; h < 2; ++h) {
        float4 o = make_float4(
          0.0625f * (__expf(A[a][h*4+0] - dg - mx) + 1e-4f),
          0.0625f * (__expf(A[a][h*4+1] - dg - mx) + 1e-4f),
          0.0625f * (__expf(A[a][h*4+2] - dg - mx) + 1e-4f),
          0.0625f * (__expf(A[a][h*4+3] - dg - mx) + 1e-4f));
        *(float4*)(outp + (size_t)(row0 + ti*4 + a) * M_ + h*128 + tj*4) = o;
      }
    }
  }
}

// Elementwise k': kp = ratio*(exp(xd - diag - kmax_bh) + eps). Block = 64 rows.
__global__ __launch_bounds__(512) void kexp_kernel(
    const float* __restrict__ k, const float* __restrict__ xd,
    const unsigned* __restrict__ kmaxE, float* __restrict__ kp)
{
  const int t = threadIdx.x;
  const int blk = blockIdx.x;
  const int row0 = blk * 64;
  __shared__ float diagS[64];
  if (t < 256) {
    int r = t >> 2, q4 = t & 3;
    const float4* src = (const float4*)(k + (size_t)(row0 + r) * 64 + q4 * 16);
    float s = 0.f;
#pragma unroll
    for (int i = 0; i < 4; ++i) { float4 f = src[i]; s += f.x*f.x + f.y*f.y + f.z*f.z + f.w*f.w; }
    s += __shfl_xor(s, 1); s += __shfl_xor(s, 2);
    if (q4 == 0) diagS[r] = 0.0625f * s;
  }
  const float mx = dec_f(kmaxE[blk >> 5]);   // bh = row0/N_
  __syncthreads();
  const size_t base = (size_t)blk * (64 * M_);
#pragma unroll
  for (int i = 0; i < 8; ++i) {
    int off = i * 2048 + t * 4;
    int r = off >> 8;             // wave-uniform
    float dg = diagS[r] + mx;
    float4 xv = *(const float4*)(xd + base + off);
    float4 o = make_float4(
      0.0625f * (__expf(xv.x - dg) + 1e-4f),
      0.0625f * (__expf(xv.y - dg) + 1e-4f),
      0.0625f * (__expf(xv.z - dg) + 1e-4f),
      0.0625f * (__expf(xv.w - dg) + 1e-4f));
    *(float4*)(kp + base + off) = o;
  }
}

// Per-chunk sums via LDS microtile: ksum[m] = sum_s k'[s][m]; kv[m][d] = sum_s k'[s][m]*v[s][d].
// Block = one chunk, 512 threads; thread owns 4m x 4d per 128-m half.
__global__ __launch_bounds__(512, 4) void chunksum_kernel(
    const float* __restrict__ kp, const float* __restrict__ v,
    float* __restrict__ ksum, float* __restrict__ kv)
{
  const int t = threadIdx.x;
  const int blk = blockIdx.x;
  const int row0 = blk * C_;
  __shared__ float vS[64][64];
  __shared__ float kS[64][128];
  {  // stage v
    int r = t >> 3, oct = t & 7;
    const float4* src = (const float4*)(v + (size_t)(row0 + r) * D_ + oct * 8);
    *(float4*)&vS[r][oct*8]     = src[0];
    *(float4*)&vS[r][oct*8 + 4] = src[1];
  }
  const int mi = t >> 4;   // 0..31
  const int dj = t & 15;   // 0..15
  for (int h = 0; h < 2; ++h) {
    __syncthreads();
    {  // stage k' half
      int r = t >> 3, oct = t & 7;
      const float4* src = (const float4*)(kp + (size_t)(row0 + r) * M_ + h*128 + oct*16);
#pragma unroll
      for (int i = 0; i < 4; ++i) *(float4*)&kS[r][oct*16 + i*4] = src[i];
    }
    __syncthreads();
    float acc[4][4] = {};
#pragma unroll 4
    for (int r = 0; r < 64; ++r) {
      float4 k4 = *(const float4*)&kS[r][mi*4];
      float4 v4 = *(const float4*)&vS[r][dj*4];
      float km[4] = {k4.x, k4.y, k4.z, k4.w};
      float vd[4] = {v4.x, v4.y, v4.z, v4.w};
#pragma unroll
      for (int a = 0; a < 4; ++a)
#pragma unroll
        for (int b = 0; b < 4; ++b)
          acc[a][b] = fmaf(km[a], vd[b], acc[a][b]);
    }
    size_t mbase = (size_t)blk * M_ + h*128 + mi*4;
#pragma unroll
    for (int a = 0; a < 4; ++a)
      *(float4*)(kv + (mbase + a) * D_ + dj*4) =
          make_float4(acc[a][0], acc[a][1], acc[a][2], acc[a][3]);
    if (t < 128) {  // column sums for ksum
      float s = 0.f;
#pragma unroll 8
      for (int r = 0; r < 64; ++r) s += kS[r][t];
      ksum[(size_t)blk * M_ + h*128 + t] = s;
    }
  }
}

// Exclusive prefix over chunks, in place. Grid = BH*64; block handles 256 of the 16384 kv elems.
__global__ __launch_bounds__(256) void scan_kernel(float* __restrict__ ksum, float* __restrict__ kv)
{
  const int t = threadIdx.x;
  const int bh = blockIdx.x >> 6;
  const int sl = blockIdx.x & 63;
  {
    size_t base = (size_t)bh * NC_ * M_ * D_ + (size_t)sl * 256 + t;
    float carry = 0.f;
    for (int ch = 0; ch < NC_; ++ch) {
      float* ptr = kv + base + (size_t)ch * (M_ * D_);
      float xv = *ptr; *ptr = carry; carry += xv;
    }
  }
  if (sl == 0) {
    size_t base = (size_t)bh * NC_ * M_ + t;
    float carry = 0.f;
    for (int ch = 0; ch < NC_; ++ch) {
      float* ptr = ksum + base + (size_t)ch * M_;
      float xv = *ptr; *ptr = carry; carry += xv;
    }
  }
}

// Per chunk: O = Q'.S_prev + tril(Q'K'^T).V ; den = Q'.ksum_prev + rowsum(tril(A)) + 1e-6*sum(Q').
__global__ __launch_bounds__(256) void out_kernel(
    const float* __restrict__ qp, const float* __restrict__ kp,
    const float* __restrict__ v, const float* __restrict__ ksE_g,
    const float* __restrict__ kvE_g, float* __restrict__ out)
{
  const int t = threadIdx.x;
  const int blk = blockIdx.x;       // bh*NC + ch
  const int row0 = blk * C_;
  const int ti = t >> 4, tj = t & 15;

  __shared__ float lds[3 * 64 * 68];
  float (*qpT)[68] = (float (*)[68])lds;                 // [j][r]
  float (*kpT)[68] = (float (*)[68])(lds + 64 * 68);     // [j][s]
  float (*SpS)[68] = (float (*)[68])(lds + 2 * 64 * 68); // [j][d]
  float (*AmT)[68] = qpT;                                // phase 2: [s][r]
  float (*vS)[68]  = kpT;                                // phase 2: [s][d]
  __shared__ float ksE[64];
  __shared__ float denS[64];

  float A[4][4] = {}, O[4][4] = {};
  float den4[4] = {}, qs4[4] = {};
  const int r = t >> 2, q4 = t & 3;

  for (int mt = 0; mt < 4; ++mt) {
    __syncthreads();
#pragma unroll
    for (int i = 0; i < 4; ++i) {
      int mo = q4 * 16 + i * 4;
      float4 f = *(const float4*)(qp + (size_t)(row0 + r) * M_ + mt * 64 + mo);
      qpT[mo+0][r] = f.x; qpT[mo+1][r] = f.y; qpT[mo+2][r] = f.z; qpT[mo+3][r] = f.w;
      float4 g = *(const float4*)(kp + (size_t)(row0 + r) * M_ + mt * 64 + mo);
      kpT[mo+0][r] = g.x; kpT[mo+1][r] = g.y; kpT[mo+2][r] = g.z; kpT[mo+3][r] = g.w;
      float4 h = *(const float4*)(kvE_g + ((size_t)blk * M_ + mt * 64 + r) * D_ + mo);
      *(float4*)&SpS[r][mo] = h;
    }
    if (t < 64) ksE[t] = ksE_g[(size_t)blk * M_ + mt * 64 + t];
    __syncthreads();

    for (int j = 0; j < 64; ++j) {
      float4 qv = *(const float4*)&qpT[j][ti * 4];
      float4 kq = *(const float4*)&kpT[j][tj * 4];
      float4 sv = *(const float4*)&SpS[j][tj * 4];
      float ksj = ksE[j];
      float qa[4] = {qv.x, qv.y, qv.z, qv.w};
      float kb[4] = {kq.x, kq.y, kq.z, kq.w};
      float sb[4] = {sv.x, sv.y, sv.z, sv.w};
#pragma unroll
      for (int a = 0; a < 4; ++a) {
#pragma unroll
        for (int b = 0; b < 4; ++b) {
          A[a][b] = fmaf(qa[a], kb[b], A[a][b]);
          O[a][b] = fmaf(qa[a], sb[b], O[a][b]);
        }
        den4[a] = fmaf(qa[a], ksj, den4[a]);
        qs4[a] += qa[a];
      }
    }
  }
  __syncthreads();  // phase-1 LDS reads done; safe to overwrite aliased regions

  // causal mask, write A^T to LDS, accumulate den_intra
  float dintra[4] = {};
#pragma unroll
  for (int a = 0; a < 4; ++a) {
    int ri = ti * 4 + a;
#pragma unroll
    for (int b = 0; b < 4; ++b) {
      int sj = tj * 4 + b;
      float av = (sj <= ri) ? A[a][b] : 0.f;
      AmT[sj][ri] = av;
      dintra[a] += av;
    }
  }
#pragma unroll
  for (int off = 1; off < 16; off <<= 1) {
#pragma unroll
    for (int a = 0; a < 4; ++a) dintra[a] += __shfl_xor(dintra[a], off);
  }
#pragma unroll
  for (int i = 0; i < 4; ++i) {   // stage v chunk
    int mo = q4 * 16 + i * 4;
    float4 f = *(const float4*)(v + (size_t)(row0 + r) * D_ + mo);
    *(float4*)&vS[r][mo] = f;
  }
  if (tj == 0) {
#pragma unroll
    for (int a = 0; a < 4; ++a)
      denS[ti * 4 + a] = den4[a] + dintra[a] + 1e-6f * qs4[a];
  }
  __syncthreads();

  for (int s = 0; s < 64; ++s) {
    float4 a4 = *(const float4*)&AmT[s][ti * 4];
    float4 vv = *(const float4*)&vS[s][tj * 4];
    float aa[4] = {a4.x, a4.y, a4.z, a4.w};
    float vb[4] = {vv.x, vv.y, vv.z, vv.w};
#pragma unroll
    for (int a = 0; a < 4; ++a)
#pragma unroll
      for (int b = 0; b < 4; ++b)
        O[a][b] = fmaf(aa[a], vb[b], O[a][b]);
  }

#pragma unroll
  for (int a = 0; a < 4; ++a) {
    float dinv = 1.f / denS[ti * 4 + a];
    float4 o4 = make_float4(O[a][0] * dinv, O[a][1] * dinv, O[a][2] * dinv, O[a][3] * dinv);
    *(float4*)(out + (size_t)(row0 + ti * 4 + a) * D_ + tj * 4) = o4;
  }
}

extern "C" void kernel_launch(void* const* d_in, const int* in_sizes, int n_in,
                              void* d_out, int out_size, void* d_ws, size_t ws_size,
                              hipStream_t stream)
{
  (void)in_sizes; (void)n_in; (void)out_size; (void)ws_size;
  const float* q    = (const float*)d_in[0];
  const float* k    = (const float*)d_in[1];
  const float* v    = (const float*)d_in[2];
  const float* proj = (const float*)d_in[3];
  float* out = (float*)d_out;

  float* ws = (float*)d_ws;
  const size_t SQP = (size_t)BH_ * N_ * M_;                 // 8,388,608 floats
  float* qp   = ws;                                         // [BH*N][M]
  float* kp   = ws + SQP;                                   // [BH*N][M]
  float* xd   = ws + 2 * SQP;                               // raw k-side xd; later reused as kv
  float* kv   = xd;                                         // aliased: xd dead after kexp
  float* ksum = ws + 3 * SQP;                               // BH*NC*M = 131072
  unsigned* kmaxE = (unsigned*)(ksum + (size_t)BH_ * NC_ * M_);
  // total ws use: ~101 MiB

  init_kernel<<<dim3(1), dim3(64), 0, stream>>>(kmaxE);
  gemm_feat<0><<<dim3(BH_ * N_ / 64), dim3(512), 0, stream>>>(k, proj, xd, kmaxE);
  gemm_feat<1><<<dim3(BH_ * N_ / 64), dim3(512), 0, stream>>>(q, proj, qp, kmaxE);
  kexp_kernel<<<dim3(BH_ * N_ / 64), dim3(512), 0, stream>>>(k, xd, kmaxE, kp);
  chunksum_kernel<<<dim3(BH_ * NC_), dim3(512), 0, stream>>>(kp, v, ksum, kv);
  scan_kernel<<<dim3(BH_ * 64), dim3(256), 0, stream>>>(ksum, kv);
  out_kernel<<<dim3(BH_ * NC_), dim3(256), 0, stream>>>(qp, kp, v, ksum, kv, out);
}

// Round 3
// 156.958 us; speedup vs baseline: 2.0532x; 1.3159x over previous
//
#include <hip/hip_runtime.h>
#include <cstddef>

typedef __attribute__((ext_vector_type(8))) short bf16x8;
typedef __attribute__((ext_vector_type(4))) float f32x4;

#define BH_ 16
#define N_ 2048
#define D_ 64
#define M_ 256
#define C_ 64
#define NC_ 32
#define NROW_ (BH_*N_)   // 32768
#define NCH_ (BH_*NC_)   // 512
#define NRM_ 0.35355339059327373f  // 64^-0.25
#define RATIO_ 0.0625f             // 256^-0.5

#define MFMA(a,b,c) __builtin_amdgcn_mfma_f32_16x16x32_bf16((a),(b),(c),0,0,0)

__device__ __forceinline__ unsigned short f2b(float f) {  // fp32 -> bf16 RNE
  unsigned u = __float_as_uint(f);
  u += 0x7FFFu + ((u >> 16) & 1u);
  return (unsigned short)(u >> 16);
}
__device__ __forceinline__ float b2f(unsigned short h) {
  return __uint_as_float(((unsigned)h) << 16);
}
__device__ __forceinline__ unsigned enc_f(float f) {
  unsigned u = __float_as_uint(f);
  return (u & 0x80000000u) ? ~u : (u | 0x80000000u);
}
__device__ __forceinline__ float dec_f(unsigned e) {
  unsigned u = (e & 0x80000000u) ? (e & 0x7FFFFFFFu) : ~e;
  return __uint_as_float(u);
}
__device__ __forceinline__ bf16x8 mk8(float4 a, float4 b) {
  bf16x8 r;
  r[0]=(short)f2b(a.x); r[1]=(short)f2b(a.y); r[2]=(short)f2b(a.z); r[3]=(short)f2b(a.w);
  r[4]=(short)f2b(b.x); r[5]=(short)f2b(b.y); r[6]=(short)f2b(b.z); r[7]=(short)f2b(b.w);
  return r;
}
__device__ __forceinline__ float sumsq4(float4 a){ return a.x*a.x+a.y*a.y+a.z*a.z+a.w*a.w; }
__device__ __forceinline__ float4 sc4(float4 f){ return make_float4(NRM_*f.x, NRM_*f.y, NRM_*f.z, NRM_*f.w); }

// prep: bf16 proj; Vext^T per chunk [ch][80][64] (col64 = 1.0 ones, col65+ = 0); init kmaxE
__global__ __launch_bounds__(256) void prep_kernel(
    const float* __restrict__ v, const float* __restrict__ proj,
    unsigned short* __restrict__ vxbT, unsigned short* __restrict__ projb,
    unsigned* __restrict__ kmaxE)
{
  int t = threadIdx.x, ch = blockIdx.x;
  if (ch == 0 && t < BH_) kmaxE[t] = 0u;
  if (ch < 64) { int idx = ch*256 + t; projb[idx] = f2b(proj[idx]); }
  for (int cell = t; cell < 80*64; cell += 256) {
    int c = cell >> 6, s = cell & 63;
    unsigned short val;
    if (c < 64)      val = f2b(v[((size_t)ch*64 + s)*64 + c]);
    else if (c==64)  val = 0x3F80;  // 1.0
    else             val = 0;
    vxbT[((size_t)ch*80 + c)*64 + s] = val;
  }
}

// feat1: blocks 0..511 -> k global-max pass; 512..1023 -> q-features (per-row max + exp -> qp bf16)
__global__ __launch_bounds__(256) void feat1_kernel(
    const float* __restrict__ qg, const float* __restrict__ kg,
    const unsigned short* __restrict__ projb,
    unsigned short* __restrict__ qp, unsigned* __restrict__ kmaxE)
{
  __shared__ unsigned short projbS[256*72];
  const int t = threadIdx.x, bb = blockIdx.x;
  const bool isq = bb >= NCH_;
  const int blk = bb & (NCH_-1);
  const float* x = isq ? qg : kg;
  const int row0 = blk * 64;
  const int w = t>>6, lane = t&63, m16 = lane&15, q4 = lane>>4;
  const int r0 = w*16;

  for (int i4 = t; i4 < 4096; i4 += 256) {       // stage proj bf16, stride 72
    int m = i4 >> 4, d4 = (i4 & 15)*4;
    *(uint2*)&projbS[m*72 + d4] = *(const uint2*)&projb[m*64 + d4];
  }
  const float* xr = x + (size_t)(row0 + r0 + m16)*64 + q4*8;
  float4 x0 = *(const float4*)(xr);
  float4 x1 = *(const float4*)(xr+4);
  float4 x2 = *(const float4*)(xr+32);
  float4 x3 = *(const float4*)(xr+36);
  float sq = sumsq4(x0)+sumsq4(x1)+sumsq4(x2)+sumsq4(x3);
  sq += __shfl_xor(sq,16); sq += __shfl_xor(sq,32);
  float diagv = 0.0625f * sq;                    // 0.5*nrm^2*sum(x^2) for row r0+m16
  bf16x8 a0 = mk8(sc4(x0), sc4(x1));
  bf16x8 a1 = mk8(sc4(x2), sc4(x3));
  __syncthreads();

  f32x4 acc[16];
#pragma unroll
  for (int mt = 0; mt < 16; ++mt) acc[mt] = (f32x4){0.f,0.f,0.f,0.f};
#pragma unroll
  for (int mt = 0; mt < 16; ++mt) {
    bf16x8 b0 = *(const bf16x8*)&projbS[(mt*16+m16)*72 + q4*8];
    bf16x8 b1 = *(const bf16x8*)&projbS[(mt*16+m16)*72 + 32 + q4*8];
    acc[mt] = MFMA(a0, b0, acc[mt]);
    acc[mt] = MFMA(a1, b1, acc[mt]);
  }

  if (!isq) {
    float mx = acc[0][0];
#pragma unroll
    for (int mt = 0; mt < 16; ++mt)
#pragma unroll
      for (int j = 0; j < 4; ++j) mx = fmaxf(mx, acc[mt][j]);
#pragma unroll
    for (int off = 1; off < 64; off <<= 1) mx = fmaxf(mx, __shfl_xor(mx, off));
    if (lane == 0) atomicMax(kmaxE + (blk >> 5), enc_f(mx));
  } else {
#pragma unroll
    for (int j = 0; j < 4; ++j) {
      float rm = acc[0][j];
#pragma unroll
      for (int mt = 1; mt < 16; ++mt) rm = fmaxf(rm, acc[mt][j]);
      rm = fmaxf(rm, __shfl_xor(rm,1));
      rm = fmaxf(rm, __shfl_xor(rm,2));
      rm = fmaxf(rm, __shfl_xor(rm,4));
      rm = fmaxf(rm, __shfl_xor(rm,8));
      float e = __shfl(diagv, q4*4 + j) + rm;
      int orow = row0 + r0 + q4*4 + j;
#pragma unroll
      for (int mt = 0; mt < 16; ++mt) {
        float val = RATIO_*(__expf(acc[mt][j] - e) + 1e-4f);
        qp[(size_t)orow*256 + mt*16 + m16] = f2b(val);
      }
    }
  }
}

// kfeat: recompute xd (MFMA), exp with per-bh kmax -> kp (row-major bf16) + LDS transpose;
// then chunk-sum GEMM C2^T[c][m] = sum_s Vext[s][c] * k'[s][m] -> kvxT bf16 (col64 = ksum)
__global__ __launch_bounds__(256) void kfeat_kernel(
    const float* __restrict__ kg, const unsigned short* __restrict__ projb,
    const unsigned short* __restrict__ vxbT, const unsigned* __restrict__ kmaxE,
    unsigned short* __restrict__ kp, unsigned short* __restrict__ kvxT)
{
  __shared__ unsigned short projbS[256*72];
  __shared__ unsigned short kpT[256*72];     // [m][s], stride 72
  const int t = threadIdx.x, ch = blockIdx.x;
  const int row0 = ch * 64;
  const int w = t>>6, lane = t&63, m16 = lane&15, q4 = lane>>4;
  const int r0 = w*16;

  for (int i4 = t; i4 < 4096; i4 += 256) {
    int m = i4 >> 4, d4 = (i4 & 15)*4;
    *(uint2*)&projbS[m*72 + d4] = *(const uint2*)&projb[m*64 + d4];
  }
  const float* xr = kg + (size_t)(row0 + r0 + m16)*64 + q4*8;
  float4 x0 = *(const float4*)(xr);
  float4 x1 = *(const float4*)(xr+4);
  float4 x2 = *(const float4*)(xr+32);
  float4 x3 = *(const float4*)(xr+36);
  float sq = sumsq4(x0)+sumsq4(x1)+sumsq4(x2)+sumsq4(x3);
  sq += __shfl_xor(sq,16); sq += __shfl_xor(sq,32);
  float diagv = 0.0625f * sq;
  bf16x8 a0 = mk8(sc4(x0), sc4(x1));
  bf16x8 a1 = mk8(sc4(x2), sc4(x3));
  const float kmx = dec_f(kmaxE[ch >> 5]);
  __syncthreads();

  f32x4 acc[16];
#pragma unroll
  for (int mt = 0; mt < 16; ++mt) acc[mt] = (f32x4){0.f,0.f,0.f,0.f};
#pragma unroll
  for (int mt = 0; mt < 16; ++mt) {
    bf16x8 b0 = *(const bf16x8*)&projbS[(mt*16+m16)*72 + q4*8];
    bf16x8 b1 = *(const bf16x8*)&projbS[(mt*16+m16)*72 + 32 + q4*8];
    acc[mt] = MFMA(a0, b0, acc[mt]);
    acc[mt] = MFMA(a1, b1, acc[mt]);
  }
#pragma unroll
  for (int j = 0; j < 4; ++j) {
    float e = __shfl(diagv, q4*4 + j) + kmx;
    int srow = r0 + q4*4 + j;
#pragma unroll
    for (int mt = 0; mt < 16; ++mt) {
      float val = RATIO_*(__expf(acc[mt][j] - e) + 1e-4f);
      unsigned short hb = f2b(val);
      kp[(size_t)(row0 + srow)*256 + mt*16 + m16] = hb;
      kpT[(mt*16+m16)*72 + srow] = hb;
    }
  }
  __syncthreads();

  // phase B: A = Vext^T (rows c), B = k' (staged [m][s]); D[c][m]
  f32x4 c2[5][4];
#pragma unroll
  for (int ct = 0; ct < 5; ++ct)
#pragma unroll
    for (int mt = 0; mt < 4; ++mt) c2[ct][mt] = (f32x4){0.f,0.f,0.f,0.f};
#pragma unroll
  for (int ct = 0; ct < 5; ++ct) {
    const unsigned short* ap = vxbT + ((size_t)ch*80 + ct*16 + m16)*64 + q4*8;
    bf16x8 va0 = *(const bf16x8*)(ap);
    bf16x8 va1 = *(const bf16x8*)(ap + 32);
#pragma unroll
    for (int mt = 0; mt < 4; ++mt) {
      bf16x8 b0 = *(const bf16x8*)&kpT[((w*4+mt)*16+m16)*72 + q4*8];
      bf16x8 b1 = *(const bf16x8*)&kpT[((w*4+mt)*16+m16)*72 + 32 + q4*8];
      c2[ct][mt] = MFMA(va0, b0, c2[ct][mt]);
      c2[ct][mt] = MFMA(va1, b1, c2[ct][mt]);
    }
  }
#pragma unroll
  for (int ct = 0; ct < 5; ++ct)
#pragma unroll
    for (int mt = 0; mt < 4; ++mt)
#pragma unroll
      for (int j = 0; j < 4; ++j)
        kvxT[((size_t)ch*80 + ct*16 + q4*4 + j)*256 + (w*4+mt)*16 + m16] = f2b(c2[ct][mt][j]);
}

// scan: exclusive prefix over the 32 chunks of each bh, transposed layout [ch][c][m];
// col 65 overwritten with the 1e-6 denominator-eps constant
__global__ __launch_bounds__(256) void scan_kernel(
    const unsigned short* __restrict__ kvxT, unsigned short* __restrict__ SxT)
{
  const int t = threadIdx.x;
  const int c = blockIdx.x % 80, bh = blockIdx.x / 80;
  size_t base = ((size_t)bh*32*80 + c)*256 + t;
  float carry = 0.f;
  const unsigned short eps = f2b(1e-6f);
  const bool is65 = (c == 65);
  for (int chl = 0; chl < 32; ++chl) {
    size_t idx = base + (size_t)chl*(80*256);
    SxT[idx] = is65 ? eps : f2b(carry);
    carry += b2f(kvxT[idx]);
  }
}

// out: per chunk, A = Q'K'^T (masked -> P via LDS) ; O = Q'*Sext + P*Vext.
// Sext col64 = ksum_prev, col65 = 1e-6 ; Vext col64 = ones -> den = O[:,64]+O[:,65]
__global__ __launch_bounds__(256) void out_kernel(
    const unsigned short* __restrict__ qp, const unsigned short* __restrict__ kp,
    const unsigned short* __restrict__ SxT, const unsigned short* __restrict__ vxbT,
    float* __restrict__ out)
{
  __shared__ unsigned short P[64*72];   // [r][s], stride 72; wave-local row slices
  const int t = threadIdx.x, ch = blockIdx.x;
  const int row0 = ch * 64;
  const int w = t>>6, lane = t&63, m16 = lane&15, q4 = lane>>4;
  const int r0 = w*16;

  f32x4 accA[4], accO[5];
#pragma unroll
  for (int i = 0; i < 4; ++i) accA[i] = (f32x4){0.f,0.f,0.f,0.f};
#pragma unroll
  for (int i = 0; i < 5; ++i) accO[i] = (f32x4){0.f,0.f,0.f,0.f};

  const unsigned short* qpR = qp + (size_t)(row0 + r0 + m16)*256 + q4*8;
  const unsigned short* kpB = kp + ((size_t)row0 + m16)*256 + q4*8;
  const unsigned short* sxB = SxT + ((size_t)ch*80 + m16)*256 + q4*8;
#pragma unroll
  for (int kk = 0; kk < 8; ++kk) {
    bf16x8 a = *(const bf16x8*)(qpR + kk*32);
#pragma unroll
    for (int st = 0; st < 4; ++st) {
      bf16x8 b = *(const bf16x8*)(kpB + (size_t)st*16*256 + kk*32);
      accA[st] = MFMA(a, b, accA[st]);
    }
#pragma unroll
    for (int ct = 0; ct < 5; ++ct) {
      bf16x8 b = *(const bf16x8*)(sxB + (size_t)ct*16*256 + kk*32);
      accO[ct] = MFMA(a, b, accO[ct]);
    }
  }
  // causal mask -> P (rows r0..r0+15 written & read by this wave only)
#pragma unroll
  for (int st = 0; st < 4; ++st)
#pragma unroll
    for (int j = 0; j < 4; ++j) {
      int rr = r0 + q4*4 + j;
      int cc = st*16 + m16;
      P[rr*72 + cc] = f2b((cc <= rr) ? accA[st][j] : 0.f);
    }
  // phase 2: O += P * Vext
#pragma unroll
  for (int k2 = 0; k2 < 2; ++k2) {
    bf16x8 aP = *(const bf16x8*)&P[(r0+m16)*72 + k2*32 + q4*8];
#pragma unroll
    for (int ct = 0; ct < 5; ++ct) {
      bf16x8 b = *(const bf16x8*)(vxbT + ((size_t)ch*80 + ct*16 + m16)*64 + k2*32 + q4*8);
      accO[ct] = MFMA(aP, b, accO[ct]);
    }
  }
  // epilogue: den broadcast + divide + store
#pragma unroll
  for (int j = 0; j < 4; ++j) {
    float d64 = __shfl(accO[4][j], (lane & 48));
    float d65 = __shfl(accO[4][j], (lane & 48) | 1);
    float dinv = 1.f / (d64 + d65);
    int orow = row0 + r0 + q4*4 + j;
#pragma unroll
    for (int ct = 0; ct < 4; ++ct)
      out[(size_t)orow*64 + ct*16 + m16] = accO[ct][j] * dinv;
  }
}

extern "C" void kernel_launch(void* const* d_in, const int* in_sizes, int n_in,
                              void* d_out, int out_size, void* d_ws, size_t ws_size,
                              hipStream_t stream)
{
  (void)in_sizes; (void)n_in; (void)out_size; (void)ws_size;
  const float* q    = (const float*)d_in[0];
  const float* k    = (const float*)d_in[1];
  const float* v    = (const float*)d_in[2];
  const float* proj = (const float*)d_in[3];
  float* out = (float*)d_out;

  char* p8 = (char*)d_ws;
  unsigned short* qp    = (unsigned short*)p8; p8 += (size_t)NROW_*256*2;   // 16.78 MB
  unsigned short* kp    = (unsigned short*)p8; p8 += (size_t)NROW_*256*2;   // 16.78 MB
  unsigned short* kvxT  = (unsigned short*)p8; p8 += (size_t)NCH_*80*256*2; // 20.97 MB
  unsigned short* SxT   = (unsigned short*)p8; p8 += (size_t)NCH_*80*256*2; // 20.97 MB
  unsigned short* vxbT  = (unsigned short*)p8; p8 += (size_t)NCH_*80*64*2;  //  5.24 MB
  unsigned short* projb = (unsigned short*)p8; p8 += 256*64*2;
  unsigned* kmaxE = (unsigned*)p8;

  prep_kernel <<<dim3(NCH_),   dim3(256), 0, stream>>>(v, proj, vxbT, projb, kmaxE);
  feat1_kernel<<<dim3(2*NCH_), dim3(256), 0, stream>>>(q, k, projb, qp, kmaxE);
  kfeat_kernel<<<dim3(NCH_),   dim3(256), 0, stream>>>(k, projb, vxbT, kmaxE, kp, kvxT);
  scan_kernel <<<dim3(BH_*80), dim3(256), 0, stream>>>(kvxT, SxT);
  out_kernel  <<<dim3(NCH_),   dim3(256), 0, stream>>>(qp, kp, SxT, vxbT, out);
}

// Round 4
// 153.605 us; speedup vs baseline: 2.0981x; 1.0218x over previous
//
#include <hip/hip_runtime.h>
#include <cstddef>

typedef __attribute__((ext_vector_type(8))) short bf16x8;
typedef __attribute__((ext_vector_type(4))) float f32x4;

#define BH_ 16
#define N_ 2048
#define D_ 64
#define M_ 256
#define C_ 64
#define NC_ 32
#define NROW_ (BH_*N_)   // 32768
#define NCH_ (BH_*NC_)   // 512
#define NRM_ 0.35355339059327373f  // 64^-0.25
#define RATIO_ 0.0625f             // 256^-0.5

#define MFMA(a,b,c) __builtin_amdgcn_mfma_f32_16x16x32_bf16((a),(b),(c),0,0,0)

__device__ __forceinline__ unsigned short f2b(float f) {  // fp32 -> bf16 RNE
  unsigned u = __float_as_uint(f);
  u += 0x7FFFu + ((u >> 16) & 1u);
  return (unsigned short)(u >> 16);
}
__device__ __forceinline__ float b2f(unsigned short h) {
  return __uint_as_float(((unsigned)h) << 16);
}
__device__ __forceinline__ unsigned enc_f(float f) {
  unsigned u = __float_as_uint(f);
  return (u & 0x80000000u) ? ~u : (u | 0x80000000u);
}
__device__ __forceinline__ float dec_f(unsigned e) {
  unsigned u = (e & 0x80000000u) ? (e & 0x7FFFFFFFu) : ~e;
  return __uint_as_float(u);
}
__device__ __forceinline__ unsigned pk2(float a, float b) {
  return (unsigned)f2b(a) | ((unsigned)f2b(b) << 16);
}
__device__ __forceinline__ bf16x8 mk8(float4 a, float4 b) {
  bf16x8 r;
  r[0]=(short)f2b(a.x); r[1]=(short)f2b(a.y); r[2]=(short)f2b(a.z); r[3]=(short)f2b(a.w);
  r[4]=(short)f2b(b.x); r[5]=(short)f2b(b.y); r[6]=(short)f2b(b.z); r[7]=(short)f2b(b.w);
  return r;
}
__device__ __forceinline__ float sumsq4(float4 a){ return a.x*a.x+a.y*a.y+a.z*a.z+a.w*a.w; }
__device__ __forceinline__ float4 sc4(float4 f){ return make_float4(NRM_*f.x, NRM_*f.y, NRM_*f.z, NRM_*f.w); }

// prep: bf16 proj; Vext^T per chunk [ch][80][64] (col64 = ones); kmax init.
// v read coalesced (float4 along d); vxbT stores are lane-contiguous in s.
__global__ __launch_bounds__(256, 4) void prep_kernel(
    const float* __restrict__ v, const float* __restrict__ proj,
    unsigned short* __restrict__ vxbT, unsigned short* __restrict__ projb,
    unsigned* __restrict__ kmaxE)
{
  const int t = threadIdx.x, ch = blockIdx.x;
  const int s = t & 63, dq = t >> 6;
  if (ch == 0 && t < BH_) kmaxE[t] = 0u;
  if (ch < 64) { int idx = ch*256 + t; projb[idx] = f2b(proj[idx]); }
  const float* vr = v + ((size_t)ch*64 + s)*64 + dq*16;
#pragma unroll
  for (int i = 0; i < 4; ++i) {
    float4 f = *(const float4*)(vr + i*4);
    int d = dq*16 + i*4;
    vxbT[((size_t)ch*80 + d+0)*64 + s] = f2b(f.x);
    vxbT[((size_t)ch*80 + d+1)*64 + s] = f2b(f.y);
    vxbT[((size_t)ch*80 + d+2)*64 + s] = f2b(f.z);
    vxbT[((size_t)ch*80 + d+3)*64 + s] = f2b(f.w);
  }
#pragma unroll
  for (int i = 0; i < 4; ++i) {
    int c = 64 + dq*4 + i;
    vxbT[((size_t)ch*80 + c)*64 + s] = (c == 64) ? 0x3F80 : 0;
  }
}

// feat1: blocks 0..511 -> k global-max; 512..1023 -> q-features.
// Swapped operands: D[feature][row]; wave tile = 64 feats x 64 rows (a-frag reuse 4x).
__global__ __launch_bounds__(256, 3) void feat1_kernel(
    const float* __restrict__ qg, const float* __restrict__ kg,
    const unsigned short* __restrict__ projb,
    unsigned short* __restrict__ qp, unsigned* __restrict__ kmaxE)
{
  __shared__ float rmS[4][64];
  const int t = threadIdx.x, bb = blockIdx.x;
  const bool isq = bb >= NCH_;
  const int blk = bb & (NCH_-1);
  const float* x = isq ? qg : kg;
  const int row0 = blk * 64;
  const int w = t>>6, lane = t&63, m16 = lane&15, q4 = lane>>4;
  const int f0 = w * 64;

  bf16x8 b[4][2];
  float diag4[4];
#pragma unroll
  for (int rt = 0; rt < 4; ++rt) {
    const float* xr = x + (size_t)(row0 + rt*16 + m16)*64 + q4*8;
    float4 x0 = *(const float4*)(xr);
    float4 x1 = *(const float4*)(xr+4);
    float4 x2 = *(const float4*)(xr+32);
    float4 x3 = *(const float4*)(xr+36);
    float sq = sumsq4(x0)+sumsq4(x1)+sumsq4(x2)+sumsq4(x3);
    sq += __shfl_xor(sq,16); sq += __shfl_xor(sq,32);
    diag4[rt] = 0.0625f * sq;           // 0.5*nrm^2*sum(x^2) for row rt*16+m16
    b[rt][0] = mk8(sc4(x0), sc4(x1));
    b[rt][1] = mk8(sc4(x2), sc4(x3));
  }

  f32x4 acc[4][4];
#pragma unroll
  for (int rt = 0; rt < 4; ++rt)
#pragma unroll
    for (int mt = 0; mt < 4; ++mt) acc[rt][mt] = (f32x4){0.f,0.f,0.f,0.f};
#pragma unroll
  for (int kk = 0; kk < 2; ++kk)
#pragma unroll
    for (int mt = 0; mt < 4; ++mt) {
      bf16x8 a = *(const bf16x8*)&projb[(size_t)(f0 + mt*16 + m16)*64 + kk*32 + q4*8];
#pragma unroll
      for (int rt = 0; rt < 4; ++rt)
        acc[rt][mt] = MFMA(a, b[rt][kk], acc[rt][mt]);
    }

  if (!isq) {
    float mx = acc[0][0][0];
#pragma unroll
    for (int rt = 0; rt < 4; ++rt)
#pragma unroll
      for (int mt = 0; mt < 4; ++mt)
#pragma unroll
        for (int j = 0; j < 4; ++j) mx = fmaxf(mx, acc[rt][mt][j]);
#pragma unroll
    for (int off = 1; off < 64; off <<= 1) mx = fmaxf(mx, __shfl_xor(mx, off));
    if (lane == 0) atomicMax(kmaxE + (blk >> 5), enc_f(mx));
  } else {
    // cross-wave per-row max (feats split across the 4 waves)
#pragma unroll
    for (int rt = 0; rt < 4; ++rt) {
      float p = acc[rt][0][0];
#pragma unroll
      for (int mt = 0; mt < 4; ++mt)
#pragma unroll
        for (int j = 0; j < 4; ++j) p = fmaxf(p, acc[rt][mt][j]);
      p = fmaxf(p, __shfl_xor(p,16)); p = fmaxf(p, __shfl_xor(p,32));
      if (q4 == 0) rmS[w][rt*16 + m16] = p;
    }
    __syncthreads();
#pragma unroll
    for (int rt = 0; rt < 4; ++rt) {
      int rr = rt*16 + m16;
      float rm = fmaxf(fmaxf(rmS[0][rr], rmS[1][rr]), fmaxf(rmS[2][rr], rmS[3][rr]));
      float e = diag4[rt] + rm;
      size_t rowoff = (size_t)(row0 + rr)*256;
#pragma unroll
      for (int mt = 0; mt < 4; ++mt) {
        float v0 = RATIO_*(__expf(acc[rt][mt][0] - e) + 1e-4f);
        float v1 = RATIO_*(__expf(acc[rt][mt][1] - e) + 1e-4f);
        float v2 = RATIO_*(__expf(acc[rt][mt][2] - e) + 1e-4f);
        float v3 = RATIO_*(__expf(acc[rt][mt][3] - e) + 1e-4f);
        *(uint2*)(qp + rowoff + f0 + mt*16 + q4*4) = make_uint2(pk2(v0,v1), pk2(v2,v3));
      }
    }
  }
}

// kfeat: recompute k xd, exp with per-bh kmax -> kp (row-major, 8B stores) + kpT LDS;
// then chunk-sum GEMM C2[c][m] = sum_s Vext[s][c]*k'[s][m] -> kvxT (col c=64 is ksum)
__global__ __launch_bounds__(256, 3) void kfeat_kernel(
    const float* __restrict__ kg, const unsigned short* __restrict__ projb,
    const unsigned short* __restrict__ vxbT, const unsigned* __restrict__ kmaxE,
    unsigned short* __restrict__ kp, unsigned short* __restrict__ kvxT)
{
  __shared__ unsigned short kpT[256*72];   // [feat][row], stride 72
  const int t = threadIdx.x, ch = blockIdx.x;
  const int row0 = ch * 64;
  const int w = t>>6, lane = t&63, m16 = lane&15, q4 = lane>>4;
  const int f0 = w * 64;

  bf16x8 b[4][2];
  float diag4[4];
#pragma unroll
  for (int rt = 0; rt < 4; ++rt) {
    const float* xr = kg + (size_t)(row0 + rt*16 + m16)*64 + q4*8;
    float4 x0 = *(const float4*)(xr);
    float4 x1 = *(const float4*)(xr+4);
    float4 x2 = *(const float4*)(xr+32);
    float4 x3 = *(const float4*)(xr+36);
    float sq = sumsq4(x0)+sumsq4(x1)+sumsq4(x2)+sumsq4(x3);
    sq += __shfl_xor(sq,16); sq += __shfl_xor(sq,32);
    diag4[rt] = 0.0625f * sq;
    b[rt][0] = mk8(sc4(x0), sc4(x1));
    b[rt][1] = mk8(sc4(x2), sc4(x3));
  }
  const float kmx = dec_f(kmaxE[ch >> 5]);

  f32x4 acc[4][4];
#pragma unroll
  for (int rt = 0; rt < 4; ++rt)
#pragma unroll
    for (int mt = 0; mt < 4; ++mt) acc[rt][mt] = (f32x4){0.f,0.f,0.f,0.f};
#pragma unroll
  for (int kk = 0; kk < 2; ++kk)
#pragma unroll
    for (int mt = 0; mt < 4; ++mt) {
      bf16x8 a = *(const bf16x8*)&projb[(size_t)(f0 + mt*16 + m16)*64 + kk*32 + q4*8];
#pragma unroll
      for (int rt = 0; rt < 4; ++rt)
        acc[rt][mt] = MFMA(a, b[rt][kk], acc[rt][mt]);
    }

#pragma unroll
  for (int rt = 0; rt < 4; ++rt) {
    float e = diag4[rt] + kmx;
    int rr = rt*16 + m16;
    size_t rowoff = (size_t)(row0 + rr)*256;
#pragma unroll
    for (int mt = 0; mt < 4; ++mt) {
      float v0 = RATIO_*(__expf(acc[rt][mt][0] - e) + 1e-4f);
      float v1 = RATIO_*(__expf(acc[rt][mt][1] - e) + 1e-4f);
      float v2 = RATIO_*(__expf(acc[rt][mt][2] - e) + 1e-4f);
      float v3 = RATIO_*(__expf(acc[rt][mt][3] - e) + 1e-4f);
      unsigned short h0=f2b(v0), h1=f2b(v1), h2=f2b(v2), h3=f2b(v3);
      *(uint2*)(kp + rowoff + f0 + mt*16 + q4*4) =
          make_uint2((unsigned)h0|((unsigned)h1<<16), (unsigned)h2|((unsigned)h3<<16));
      int fb = f0 + mt*16 + q4*4;
      kpT[(fb+0)*72 + rr] = h0;
      kpT[(fb+1)*72 + rr] = h1;
      kpT[(fb+2)*72 + rr] = h2;
      kpT[(fb+3)*72 + rr] = h3;
    }
  }
  __syncthreads();

  // phase B: A = Vext^T (rows c), B = k'^T from kpT [m][s]; D[c][m]
  f32x4 c2[5][4];
#pragma unroll
  for (int ct = 0; ct < 5; ++ct)
#pragma unroll
    for (int mt = 0; mt < 4; ++mt) c2[ct][mt] = (f32x4){0.f,0.f,0.f,0.f};
#pragma unroll
  for (int ct = 0; ct < 5; ++ct) {
    const unsigned short* ap = vxbT + ((size_t)ch*80 + ct*16 + m16)*64 + q4*8;
    bf16x8 va0 = *(const bf16x8*)(ap);
    bf16x8 va1 = *(const bf16x8*)(ap + 32);
#pragma unroll
    for (int mt = 0; mt < 4; ++mt) {
      bf16x8 b0 = *(const bf16x8*)&kpT[((w*4+mt)*16+m16)*72 + q4*8];
      bf16x8 b1 = *(const bf16x8*)&kpT[((w*4+mt)*16+m16)*72 + 32 + q4*8];
      c2[ct][mt] = MFMA(va0, b0, c2[ct][mt]);
      c2[ct][mt] = MFMA(va1, b1, c2[ct][mt]);
    }
  }
#pragma unroll
  for (int ct = 0; ct < 5; ++ct)
#pragma unroll
    for (int mt = 0; mt < 4; ++mt)
#pragma unroll
      for (int j = 0; j < 4; ++j)
        kvxT[((size_t)ch*80 + ct*16 + q4*4 + j)*256 + (w*4+mt)*16 + m16] = f2b(c2[ct][mt][j]);
}

// scan: exclusive prefix over 32 chunks; all 32 loads issued independently, then prefix+store.
__global__ __launch_bounds__(256, 4) void scan_kernel(
    const unsigned short* __restrict__ kvxT, unsigned short* __restrict__ SxT)
{
  const int t = threadIdx.x;
  const int c = blockIdx.x % 80, bh = blockIdx.x / 80;
  size_t base = ((size_t)bh*32*80 + c)*256 + t;
  float vals[32];
#pragma unroll
  for (int chl = 0; chl < 32; ++chl)
    vals[chl] = b2f(kvxT[base + (size_t)chl*(80*256)]);
  float carry = 0.f;
  const unsigned short eps = f2b(1e-6f);
  const bool is65 = (c == 65);
#pragma unroll
  for (int chl = 0; chl < 32; ++chl) {
    SxT[base + (size_t)chl*(80*256)] = is65 ? eps : f2b(carry);
    carry += vals[chl];
  }
}

// out: A = Q'K'^T (masked -> P) ; O = Q'*Sext + P*Vext ; den = O[:,64]+O[:,65].
// kp-chunk + SxT staged once in LDS (shared by all 4 waves); P aliases kp region.
__global__ __launch_bounds__(256, 2) void out_kernel(
    const unsigned short* __restrict__ qp, const unsigned short* __restrict__ kp,
    const unsigned short* __restrict__ SxT, const unsigned short* __restrict__ vxbT,
    float* __restrict__ out)
{
  __shared__ unsigned short ldsS[144*264];   // 76 KB: kpS [64][264] + SxS [80][264]
  unsigned short* P = ldsS;                  // phase 2: [r][s], stride 72 (aliases kpS)
  const int t = threadIdx.x, ch = blockIdx.x;
  const int row0 = ch * 64;
  const int w = t>>6, lane = t&63, m16 = lane&15, q4 = lane>>4;
  const int r0 = w*16;

  {  // stage kp chunk + Sx chunk
    int srow = t>>2, scol = (t&3)*64;
    const unsigned short* src = kp + ((size_t)row0 + srow)*256 + scol;
#pragma unroll
    for (int i = 0; i < 8; ++i)
      *(uint4*)&ldsS[srow*264 + scol + i*8] = *(const uint4*)(src + i*8);
    for (int rr = srow; rr < 80; rr += 64) {
      const unsigned short* s2 = SxT + ((size_t)ch*80 + rr)*256 + scol;
#pragma unroll
      for (int i = 0; i < 8; ++i)
        *(uint4*)&ldsS[(64+rr)*264 + scol + i*8] = *(const uint4*)(s2 + i*8);
    }
  }
  __syncthreads();

  f32x4 accA[4], accO[5];
#pragma unroll
  for (int i = 0; i < 4; ++i) accA[i] = (f32x4){0.f,0.f,0.f,0.f};
#pragma unroll
  for (int i = 0; i < 5; ++i) accO[i] = (f32x4){0.f,0.f,0.f,0.f};

  const unsigned short* qpR = qp + (size_t)(row0 + r0 + m16)*256 + q4*8;
#pragma unroll
  for (int kk = 0; kk < 8; ++kk) {
    bf16x8 a = *(const bf16x8*)(qpR + kk*32);
#pragma unroll
    for (int st = 0; st < 4; ++st) {
      bf16x8 b = *(const bf16x8*)&ldsS[(st*16+m16)*264 + kk*32 + q4*8];
      accA[st] = MFMA(a, b, accA[st]);
    }
#pragma unroll
    for (int ct = 0; ct < 5; ++ct) {
      bf16x8 b = *(const bf16x8*)&ldsS[(64+ct*16+m16)*264 + kk*32 + q4*8];
      accO[ct] = MFMA(a, b, accO[ct]);
    }
  }
  __syncthreads();   // all LDS reads done; safe to overwrite with P

  // causal mask -> P (rows r0..r0+15 written & read by this wave only)
#pragma unroll
  for (int st = 0; st < 4; ++st)
#pragma unroll
    for (int j = 0; j < 4; ++j) {
      int rr = r0 + q4*4 + j;
      int cc = st*16 + m16;
      P[rr*72 + cc] = f2b((cc <= rr) ? accA[st][j] : 0.f);
    }
  // phase 2: O += P * Vext
#pragma unroll
  for (int k2 = 0; k2 < 2; ++k2) {
    bf16x8 aP = *(const bf16x8*)&P[(r0+m16)*72 + k2*32 + q4*8];
#pragma unroll
    for (int ct = 0; ct < 5; ++ct) {
      bf16x8 b = *(const bf16x8*)(vxbT + ((size_t)ch*80 + ct*16 + m16)*64 + k2*32 + q4*8);
      accO[ct] = MFMA(aP, b, accO[ct]);
    }
  }
  // epilogue: den broadcast + divide + store
#pragma unroll
  for (int j = 0; j < 4; ++j) {
    float d64 = __shfl(accO[4][j], (lane & 48));
    float d65 = __shfl(accO[4][j], (lane & 48) | 1);
    float dinv = 1.f / (d64 + d65);
    int orow = row0 + r0 + q4*4 + j;
#pragma unroll
    for (int ct = 0; ct < 4; ++ct)
      out[(size_t)orow*64 + ct*16 + m16] = accO[ct][j] * dinv;
  }
}

extern "C" void kernel_launch(void* const* d_in, const int* in_sizes, int n_in,
                              void* d_out, int out_size, void* d_ws, size_t ws_size,
                              hipStream_t stream)
{
  (void)in_sizes; (void)n_in; (void)out_size; (void)ws_size;
  const float* q    = (const float*)d_in[0];
  const float* k    = (const float*)d_in[1];
  const float* v    = (const float*)d_in[2];
  const float* proj = (const float*)d_in[3];
  float* out = (float*)d_out;

  char* p8 = (char*)d_ws;
  unsigned short* qp    = (unsigned short*)p8; p8 += (size_t)NROW_*256*2;   // 16.78 MB
  unsigned short* kp    = (unsigned short*)p8; p8 += (size_t)NROW_*256*2;   // 16.78 MB
  unsigned short* kvxT  = (unsigned short*)p8; p8 += (size_t)NCH_*80*256*2; // 20.97 MB
  unsigned short* SxT   = (unsigned short*)p8; p8 += (size_t)NCH_*80*256*2; // 20.97 MB
  unsigned short* vxbT  = (unsigned short*)p8; p8 += (size_t)NCH_*80*64*2;  //  5.24 MB
  unsigned short* projb = (unsigned short*)p8; p8 += 256*64*2;
  unsigned* kmaxE = (unsigned*)p8;

  prep_kernel <<<dim3(NCH_),   dim3(256), 0, stream>>>(v, proj, vxbT, projb, kmaxE);
  feat1_kernel<<<dim3(2*NCH_), dim3(256), 0, stream>>>(q, k, projb, qp, kmaxE);
  kfeat_kernel<<<dim3(NCH_),   dim3(256), 0, stream>>>(k, projb, vxbT, kmaxE, kp, kvxT);
  scan_kernel <<<dim3(BH_*80), dim3(256), 0, stream>>>(kvxT, SxT);
  out_kernel  <<<dim3(NCH_),   dim3(256), 0, stream>>>(qp, kp, SxT, vxbT, out);
}

// Round 5
// 145.473 us; speedup vs baseline: 2.2154x; 1.0559x over previous
//
#include <hip/hip_runtime.h>
#include <hip/hip_bf16.h>
#include <cstddef>

typedef __attribute__((ext_vector_type(8))) short bf16x8;
typedef __attribute__((ext_vector_type(4))) float f32x4;

#define BH_ 16
#define N_ 2048
#define NC_ 32
#define NCH_ (BH_*NC_)          // 512
#define NROW_ (BH_*N_)          // 32768
#define NRM_ 0.35355339059327373f  // 64^-0.25
#define RATIO_ 0.0625f             // 256^-0.5
#define MFMA(a,b,c) __builtin_amdgcn_mfma_f32_16x16x32_bf16((a),(b),(c),0,0,0)

__device__ __forceinline__ unsigned short f2b(float f) {  // fp32 -> bf16 RNE
  unsigned u = __float_as_uint(f);
  u += 0x7FFFu + ((u >> 16) & 1u);
  return (unsigned short)(u >> 16);
}
__device__ __forceinline__ float b2f(unsigned short h) {
  return __uint_as_float(((unsigned)h) << 16);
}
__device__ __forceinline__ unsigned enc_f(float f) {
  unsigned u = __float_as_uint(f);
  return (u & 0x80000000u) ? ~u : (u | 0x80000000u);
}
__device__ __forceinline__ float dec_f(unsigned e) {
  unsigned u = (e & 0x80000000u) ? (e & 0x7FFFFFFFu) : ~e;
  return __uint_as_float(u);
}
__device__ __forceinline__ unsigned pk2f(float a, float b) {  // v_cvt_pk_bf16_f32
  union { __hip_bfloat162 h; unsigned u; } cv;
  cv.h = __float22bfloat162_rn(make_float2(a, b));
  return cv.u;
}
__device__ __forceinline__ bf16x8 cvt8(float4 a, float4 b) {
  union { bf16x8 v; unsigned u[4]; } r;
  r.u[0]=pk2f(a.x,a.y); r.u[1]=pk2f(a.z,a.w);
  r.u[2]=pk2f(b.x,b.y); r.u[3]=pk2f(b.z,b.w);
  return r.v;
}
__device__ __forceinline__ float sumsq4(float4 a){ return a.x*a.x+a.y*a.y+a.z*a.z+a.w*a.w; }
__device__ __forceinline__ float4 sc4(float4 f){ return make_float4(NRM_*f.x,NRM_*f.y,NRM_*f.z,NRM_*f.w); }

// prep: bf16 proj; Vext^T per chunk [ch][c 80][s 64] (c=64 ones); v read coalesced via LDS.
__global__ __launch_bounds__(256, 4) void prep_kernel(
    const float* __restrict__ v, const float* __restrict__ proj,
    unsigned short* __restrict__ vxbT, unsigned short* __restrict__ projb,
    unsigned* __restrict__ kmaxE)
{
  __shared__ float vS[64*68];
  const int t = threadIdx.x, ch = blockIdx.x;
  if (ch == 0 && t < BH_) kmaxE[t] = 0u;
  if (ch < 64) { int idx = ch*256 + t; projb[idx] = f2b(proj[idx]); }
  const float* vg = v + (size_t)ch*4096;
#pragma unroll
  for (int i=0;i<4;++i){ int flat=i*1024+t*4; int s=flat>>6, d=flat&63;
    *(float4*)&vS[s*68+d] = *(const float4*)(vg+flat); }
  __syncthreads();
  const int w=t>>6, lane=t&63;
  const int c = w*16 + (lane&15), sub = lane>>4;
  unsigned u[8];
#pragma unroll
  for (int j=0;j<8;++j)
    u[j] = pk2f(vS[(sub*16+2*j)*68 + c], vS[(sub*16+2*j+1)*68 + c]);
  unsigned short* dst = vxbT + ((size_t)ch*80 + c)*64 + sub*16;
  *(uint4*)(dst)   = make_uint4(u[0],u[1],u[2],u[3]);
  *(uint4*)(dst+8) = make_uint4(u[4],u[5],u[6],u[7]);
  {  // ext rows 64..79: ones then zeros
    int cc = 64 + (t>>4);
    unsigned short hv = (cc==64) ? (unsigned short)0x3F80 : (unsigned short)0;
    unsigned pv = (unsigned)hv | ((unsigned)hv<<16);
    unsigned short* d2 = vxbT + ((size_t)ch*80 + cc)*64 + (t&15)*4;
    *(uint2*)d2 = make_uint2(pv,pv);
  }
}

// feat1: blocks 0..511 -> k global-max pass; 512..1023 -> q-features.
// proj + x staged in LDS (coalesced); q' epilogue via LDS tile -> flat coalesced store.
__global__ __launch_bounds__(256, 2) void feat1_kernel(
    const float* __restrict__ qg, const float* __restrict__ kg,
    const unsigned short* __restrict__ projb,
    unsigned short* __restrict__ qp, unsigned* __restrict__ kmaxE)
{
  __shared__ unsigned short R0[256*72];     // proj staging; later q'-tile [64][264]
  __shared__ float xS[64*68];
  __shared__ float rmS[4][64];
  const int t=threadIdx.x, bb=blockIdx.x;
  const bool isq = bb >= NCH_;
  const int blk = bb & (NCH_-1);
  const float* x = isq ? qg : kg;
  const int row0 = blk*64;
  const int lane=t&63, m16=lane&15, q4=lane>>4, w=t>>6;
  const int f0 = w*64;

#pragma unroll
  for (int i=0;i<8;++i){ int flat=i*2048+t*8; int f=flat>>6, d2=flat&63;
    *(uint4*)&R0[f*72+d2] = *(const uint4*)(projb+flat); }
  const float* xg = x + (size_t)row0*64;
#pragma unroll
  for (int i=0;i<4;++i){ int flat=i*1024+t*4; int r=flat>>6, d2=flat&63;
    *(float4*)&xS[r*68+d2] = *(const float4*)(xg+flat); }
  __syncthreads();

  bf16x8 b[4][2]; float diag4[4];
#pragma unroll
  for (int rt=0;rt<4;++rt){
    const float* xr = &xS[(rt*16+m16)*68 + q4*8];
    float4 x0=*(const float4*)(xr), x1=*(const float4*)(xr+4);
    float4 x2=*(const float4*)(xr+32), x3=*(const float4*)(xr+36);
    float sq = sumsq4(x0)+sumsq4(x1)+sumsq4(x2)+sumsq4(x3);
    sq += __shfl_xor(sq,16); sq += __shfl_xor(sq,32);
    diag4[rt] = 0.0625f*sq;
    b[rt][0]=cvt8(sc4(x0),sc4(x1)); b[rt][1]=cvt8(sc4(x2),sc4(x3));
  }

  f32x4 acc[4][4];
#pragma unroll
  for (int rt=0;rt<4;++rt)
#pragma unroll
    for (int mt=0;mt<4;++mt) acc[rt][mt] = (f32x4){0.f,0.f,0.f,0.f};
#pragma unroll
  for (int kk=0;kk<2;++kk)
#pragma unroll
    for (int mt=0;mt<4;++mt){
      bf16x8 a = *(const bf16x8*)&R0[(f0+mt*16+m16)*72 + kk*32 + q4*8];
#pragma unroll
      for (int rt=0;rt<4;++rt)
        acc[rt][mt] = MFMA(a, b[rt][kk], acc[rt][mt]);
    }

  if (!isq) {
    float mx = acc[0][0][0];
#pragma unroll
    for (int rt=0;rt<4;++rt)
#pragma unroll
      for (int mt=0;mt<4;++mt)
#pragma unroll
        for (int j=0;j<4;++j) mx = fmaxf(mx, acc[rt][mt][j]);
#pragma unroll
    for (int off=1; off<64; off<<=1) mx = fmaxf(mx, __shfl_xor(mx, off));
    if (lane == 0) atomicMax(kmaxE + (blk>>5), enc_f(mx));
  } else {
    unsigned short* qS = R0;
#pragma unroll
    for (int rt=0;rt<4;++rt){
      float p = acc[rt][0][0];
#pragma unroll
      for (int mt=0;mt<4;++mt)
#pragma unroll
        for (int j=0;j<4;++j) p = fmaxf(p, acc[rt][mt][j]);
      p = fmaxf(p, __shfl_xor(p,16)); p = fmaxf(p, __shfl_xor(p,32));
      if (q4 == 0) rmS[w][rt*16+m16] = p;
    }
    __syncthreads();   // rmS ready; proj reads done -> qS overlay safe
#pragma unroll
    for (int rt=0;rt<4;++rt){
      int rr = rt*16+m16;
      float rm = fmaxf(fmaxf(rmS[0][rr],rmS[1][rr]),fmaxf(rmS[2][rr],rmS[3][rr]));
      float e = diag4[rt] + rm;
#pragma unroll
      for (int mt=0;mt<4;++mt){
        float v0 = RATIO_*(__expf(acc[rt][mt][0]-e)+1e-4f);
        float v1 = RATIO_*(__expf(acc[rt][mt][1]-e)+1e-4f);
        float v2 = RATIO_*(__expf(acc[rt][mt][2]-e)+1e-4f);
        float v3 = RATIO_*(__expf(acc[rt][mt][3]-e)+1e-4f);
        *(uint2*)&qS[rr*264 + f0 + mt*16 + q4*4] = make_uint2(pk2f(v0,v1), pk2f(v2,v3));
      }
    }
    __syncthreads();
#pragma unroll
    for (int i=0;i<8;++i){ int flat=i*2048+t*8; int r=flat>>8, c2=flat&255;
      *(uint4*)(qp + (size_t)row0*256 + flat) = *(const uint4*)&qS[r*264 + c2]; }
  }
}

// kfeat: recompute k xd (MFMA), exp -> kp tile (LDS) -> coalesced store;
// phase B chunk-sum GEMM -> kvxT in fragment-packed layout (fully coalesced stores).
__global__ __launch_bounds__(256, 2) void kfeat_kernel(
    const float* __restrict__ kg, const unsigned short* __restrict__ projb,
    const unsigned short* __restrict__ vxbT, const unsigned* __restrict__ kmaxE,
    unsigned short* __restrict__ kp, unsigned short* __restrict__ kvxT)
{
  __shared__ unsigned short R0[256*72];   // proj; later kp-tile [64][264]
  __shared__ float xS[64*68];             // x; later vextS [80][72] u16
  const int t=threadIdx.x, ch=blockIdx.x;
  const int row0 = ch*64;
  const int lane=t&63, m16=lane&15, q4=lane>>4, w=t>>6;
  const int f0 = w*64;

#pragma unroll
  for (int i=0;i<8;++i){ int flat=i*2048+t*8; int f=flat>>6, d2=flat&63;
    *(uint4*)&R0[f*72+d2] = *(const uint4*)(projb+flat); }
  const float* xg = kg + (size_t)row0*64;
#pragma unroll
  for (int i=0;i<4;++i){ int flat=i*1024+t*4; int r=flat>>6, d2=flat&63;
    *(float4*)&xS[r*68+d2] = *(const float4*)(xg+flat); }
  __syncthreads();

  bf16x8 b[4][2]; float diag4[4];
#pragma unroll
  for (int rt=0;rt<4;++rt){
    const float* xr = &xS[(rt*16+m16)*68 + q4*8];
    float4 x0=*(const float4*)(xr), x1=*(const float4*)(xr+4);
    float4 x2=*(const float4*)(xr+32), x3=*(const float4*)(xr+36);
    float sq = sumsq4(x0)+sumsq4(x1)+sumsq4(x2)+sumsq4(x3);
    sq += __shfl_xor(sq,16); sq += __shfl_xor(sq,32);
    diag4[rt] = 0.0625f*sq;
    b[rt][0]=cvt8(sc4(x0),sc4(x1)); b[rt][1]=cvt8(sc4(x2),sc4(x3));
  }
  const float kmx = dec_f(kmaxE[ch>>5]);

  f32x4 acc[4][4];
#pragma unroll
  for (int rt=0;rt<4;++rt)
#pragma unroll
    for (int mt=0;mt<4;++mt) acc[rt][mt] = (f32x4){0.f,0.f,0.f,0.f};
#pragma unroll
  for (int kk=0;kk<2;++kk)
#pragma unroll
    for (int mt=0;mt<4;++mt){
      bf16x8 a = *(const bf16x8*)&R0[(f0+mt*16+m16)*72 + kk*32 + q4*8];
#pragma unroll
      for (int rt=0;rt<4;++rt)
        acc[rt][mt] = MFMA(a, b[rt][kk], acc[rt][mt]);
    }
  __syncthreads();   // proj/x reads done -> overlays safe

  unsigned short* kpS = R0;                     // [64][264]
  unsigned short* vextS = (unsigned short*)xS;  // [80][72]
#pragma unroll
  for (int rt=0;rt<4;++rt){
    float e = diag4[rt] + kmx;
    int rr = rt*16+m16;
#pragma unroll
    for (int mt=0;mt<4;++mt){
      float v0 = RATIO_*(__expf(acc[rt][mt][0]-e)+1e-4f);
      float v1 = RATIO_*(__expf(acc[rt][mt][1]-e)+1e-4f);
      float v2 = RATIO_*(__expf(acc[rt][mt][2]-e)+1e-4f);
      float v3 = RATIO_*(__expf(acc[rt][mt][3]-e)+1e-4f);
      *(uint2*)&kpS[rr*264 + f0 + mt*16 + q4*4] = make_uint2(pk2f(v0,v1), pk2f(v2,v3));
    }
  }
  {
    const unsigned short* vsrc = vxbT + (size_t)ch*80*64;
#pragma unroll
    for (int i=0;i<5;++i){ int flat=i*2048+t*8; int c=flat>>6, s=flat&63;
      *(uint4*)&vextS[c*72+s] = *(const uint4*)(vsrc+flat); }
  }
  __syncthreads();

  // coalesced kp store
#pragma unroll
  for (int i=0;i<8;++i){ int flat=i*2048+t*8; int r=flat>>8, c2=flat&255;
    *(uint4*)(kp + (size_t)row0*256 + flat) = *(const uint4*)&kpS[r*264 + c2]; }

  // phase B: C2[c][m] = sum_s Vext^T[c][s] * k'[s][m]
  f32x4 c2a[5][4];
#pragma unroll
  for (int ct=0;ct<5;++ct)
#pragma unroll
    for (int mt=0;mt<4;++mt) c2a[ct][mt] = (f32x4){0.f,0.f,0.f,0.f};
#pragma unroll
  for (int kk=0;kk<2;++kk){
    bf16x8 av[5];
#pragma unroll
    for (int ct=0;ct<5;++ct)
      av[ct] = *(const bf16x8*)&vextS[(ct*16+m16)*72 + kk*32 + q4*8];
#pragma unroll
    for (int mt=0;mt<4;++mt){
      int fcol = (w*4+mt)*16 + m16;
      int sbase = kk*32 + q4*8;
      union { bf16x8 v; unsigned u[4]; } bf;
#pragma unroll
      for (int jj=0;jj<4;++jj){
        unsigned lo = kpS[(sbase+2*jj)*264 + fcol];
        unsigned hi = kpS[(sbase+2*jj+1)*264 + fcol];
        bf.u[jj] = lo | (hi<<16);
      }
#pragma unroll
      for (int ct=0;ct<5;++ct)
        c2a[ct][mt] = MFMA(av[ct], bf.v, c2a[ct][mt]);
    }
  }
  // kvxT packed layout: [ch][ct(5)][mtile(16)][m16(16)][c16(16)] -> coalesced uint2 stores
#pragma unroll
  for (int ct=0;ct<5;++ct)
#pragma unroll
    for (int mt=0;mt<4;++mt){
      size_t base = ((((size_t)ch*5 + ct)*16 + (w*4+mt))*16 + m16)*16 + q4*4;
      *(uint2*)(kvxT + base) = make_uint2(pk2f(c2a[ct][mt][0],c2a[ct][mt][1]),
                                          pk2f(c2a[ct][mt][2],c2a[ct][mt][3]));
    }
}

// scan: exclusive prefix over 32 chunks; reads packed kvxT coalesced, LDS-transposes,
// writes SxT [ch][c 80][m 256] coalesced. Block = (bh, ct, m-half). c=65 -> 1e-6 eps.
__global__ __launch_bounds__(256, 2) void scan_kernel(
    const unsigned short* __restrict__ kvxT, unsigned short* __restrict__ SxT)
{
  __shared__ unsigned short tile[16*136];
  const int t = threadIdx.x;
  const int mh = blockIdx.x & 1;
  const int ct = (blockIdx.x >> 1) % 5;
  const int bh = blockIdx.x / 10;
  float carry[8];
#pragma unroll
  for (int i=0;i<8;++i) carry[i]=0.f;
  const int mloc = t >> 1;              // tile col for this thread's 8 elems
  const int cc0  = 8*(t&1);
  const int cc2 = t>>4, mcol = (t&15)*8;  // store mapping
  for (int ch=0; ch<32; ++ch){
#pragma unroll
    for (int i=0;i<8;++i){
      int cglob = ct*16 + cc0 + i;
      float val = (cglob==65) ? 1e-6f : carry[i];
      tile[(cc0+i)*136 + mloc] = f2b(val);
    }
    __syncthreads();
    *(uint4*)(SxT + ((size_t)(bh*32+ch)*80 + ct*16 + cc2)*256 + mh*128 + mcol) =
        *(const uint4*)&tile[cc2*136 + mcol];
    size_t kbase = (((size_t)(bh*32+ch)*5 + ct)*16 + mh*8)*256;
    uint4 raw = *(const uint4*)(kvxT + kbase + t*8);
    const unsigned short* rp = (const unsigned short*)&raw;
#pragma unroll
    for (int i=0;i<8;++i) carry[i] += b2f(rp[i]);
    __syncthreads();
  }
}

// out: A = Q'K'^T (masked -> P) ; O = Q'*Sext + P*Vext ; den = O[:,64]+O[:,65].
// kp + Sx staged in LDS (coalesced); vext staged in LDS; output via LDS tile, coalesced.
__global__ __launch_bounds__(256, 2) void out_kernel(
    const unsigned short* __restrict__ qp, const unsigned short* __restrict__ kp,
    const unsigned short* __restrict__ SxT, const unsigned short* __restrict__ vxbT,
    float* __restrict__ out_g)
{
  __shared__ unsigned short ldsS[144*264];   // 76KB: kpS [64][264] + SxS [80][264]
  unsigned short* P  = ldsS;                 // phase2: [64][72]
  unsigned short* vx = ldsS + 64*72;         // phase2: [80][72]
  float* oT = (float*)(ldsS + 64*264);       // epilogue: [64][68] fp32
  const int t=threadIdx.x, ch=blockIdx.x;
  const int row0 = ch*64;
  const int lane=t&63, m16=lane&15, q4=lane>>4, w=t>>6;
  const int r0 = w*16;

  {
    const unsigned short* ksrc = kp + (size_t)row0*256;
#pragma unroll
    for (int i=0;i<8;++i){ int flat=i*2048+t*8; int r=flat>>8, c2=flat&255;
      *(uint4*)&ldsS[r*264+c2] = *(const uint4*)(ksrc+flat); }
    const unsigned short* ssrc = SxT + (size_t)ch*80*256;
#pragma unroll
    for (int i=0;i<10;++i){ int flat=i*2048+t*8; int r=flat>>8, c2=flat&255;
      *(uint4*)&ldsS[(64+r)*264+c2] = *(const uint4*)(ssrc+flat); }
  }
  __syncthreads();

  f32x4 accA[4], accO[5];
#pragma unroll
  for (int i=0;i<4;++i) accA[i] = (f32x4){0.f,0.f,0.f,0.f};
#pragma unroll
  for (int i=0;i<5;++i) accO[i] = (f32x4){0.f,0.f,0.f,0.f};

  const unsigned short* qpR = qp + (size_t)(row0 + r0 + m16)*256 + q4*8;
#pragma unroll
  for (int kk=0;kk<8;++kk){
    bf16x8 a = *(const bf16x8*)(qpR + kk*32);
#pragma unroll
    for (int st=0;st<4;++st){
      bf16x8 bfr = *(const bf16x8*)&ldsS[(st*16+m16)*264 + kk*32 + q4*8];
      accA[st] = MFMA(a, bfr, accA[st]);
    }
#pragma unroll
    for (int ct=0;ct<5;++ct){
      bf16x8 bfr = *(const bf16x8*)&ldsS[(64+ct*16+m16)*264 + kk*32 + q4*8];
      accO[ct] = MFMA(a, bfr, accO[ct]);
    }
  }
  __syncthreads();   // phase-1 LDS reads done

  // causal mask -> P ; stage vext
#pragma unroll
  for (int st=0;st<4;++st)
#pragma unroll
    for (int j=0;j<4;++j){
      int rr = r0 + q4*4 + j;
      int cc = st*16 + m16;
      P[rr*72 + cc] = f2b((cc<=rr) ? accA[st][j] : 0.f);
    }
  {
    const unsigned short* vsrc = vxbT + (size_t)ch*80*64;
#pragma unroll
    for (int i=0;i<5;++i){ int flat=i*2048+t*8; int c=flat>>6, s=flat&63;
      *(uint4*)&vx[c*72+s] = *(const uint4*)(vsrc+flat); }
  }
  __syncthreads();

#pragma unroll
  for (int k2=0;k2<2;++k2){
    bf16x8 aP = *(const bf16x8*)&P[(r0+m16)*72 + k2*32 + q4*8];
#pragma unroll
    for (int ct=0;ct<5;++ct){
      bf16x8 bfr = *(const bf16x8*)&vx[(ct*16+m16)*72 + k2*32 + q4*8];
      accO[ct] = MFMA(aP, bfr, accO[ct]);
    }
  }
#pragma unroll
  for (int j=0;j<4;++j){
    float d64 = __shfl(accO[4][j], (lane & 48));
    float d65 = __shfl(accO[4][j], (lane & 48) | 1);
    float dinv = 1.f/(d64+d65);
    int rr = r0 + q4*4 + j;
#pragma unroll
    for (int ct=0;ct<4;++ct)
      oT[rr*68 + ct*16 + m16] = accO[ct][j]*dinv;
  }
  __syncthreads();
#pragma unroll
  for (int i=0;i<4;++i){ int flat=i*1024+t*4; int r=flat>>6, c2=flat&63;
    *(float4*)(out_g + (size_t)row0*64 + flat) = *(const float4*)&oT[r*68+c2]; }
}

extern "C" void kernel_launch(void* const* d_in, const int* in_sizes, int n_in,
                              void* d_out, int out_size, void* d_ws, size_t ws_size,
                              hipStream_t stream)
{
  (void)in_sizes; (void)n_in; (void)out_size; (void)ws_size;
  const float* q    = (const float*)d_in[0];
  const float* k    = (const float*)d_in[1];
  const float* v    = (const float*)d_in[2];
  const float* proj = (const float*)d_in[3];
  float* out = (float*)d_out;

  char* p8 = (char*)d_ws;
  unsigned short* qp    = (unsigned short*)p8; p8 += (size_t)NROW_*256*2;   // 16.78 MB
  unsigned short* kp    = (unsigned short*)p8; p8 += (size_t)NROW_*256*2;   // 16.78 MB
  unsigned short* kvxT  = (unsigned short*)p8; p8 += (size_t)NCH_*80*256*2; // 20.97 MB (packed)
  unsigned short* SxT   = (unsigned short*)p8; p8 += (size_t)NCH_*80*256*2; // 20.97 MB
  unsigned short* vxbT  = (unsigned short*)p8; p8 += (size_t)NCH_*80*64*2;  //  5.24 MB
  unsigned short* projb = (unsigned short*)p8; p8 += 256*64*2;
  unsigned* kmaxE = (unsigned*)p8;

  prep_kernel <<<dim3(NCH_),    dim3(256), 0, stream>>>(v, proj, vxbT, projb, kmaxE);
  feat1_kernel<<<dim3(2*NCH_),  dim3(256), 0, stream>>>(q, k, projb, qp, kmaxE);
  kfeat_kernel<<<dim3(NCH_),    dim3(256), 0, stream>>>(k, projb, vxbT, kmaxE, kp, kvxT);
  scan_kernel <<<dim3(BH_*10),  dim3(256), 0, stream>>>(kvxT, SxT);
  out_kernel  <<<dim3(NCH_),    dim3(256), 0, stream>>>(qp, kp, SxT, vxbT, out);
}

// Round 6
// 134.636 us; speedup vs baseline: 2.3937x; 1.0805x over previous
//
#include <hip/hip_runtime.h>
#include <hip/hip_bf16.h>
#include <cstddef>

typedef __attribute__((ext_vector_type(8))) short bf16x8;
typedef __attribute__((ext_vector_type(4))) float f32x4;

#define BH_ 16
#define N_ 2048
#define NC_ 32
#define NCH_ (BH_*NC_)          // 512
#define NROW_ (BH_*N_)          // 32768
#define NRM_ 0.35355339059327373f  // 64^-0.25
#define RATIO_ 0.0625f             // 256^-0.5
#define MFMA(a,b,c) __builtin_amdgcn_mfma_f32_16x16x32_bf16((a),(b),(c),0,0,0)

__device__ __forceinline__ unsigned short f2b(float f) {
  unsigned u = __float_as_uint(f);
  u += 0x7FFFu + ((u >> 16) & 1u);
  return (unsigned short)(u >> 16);
}
__device__ __forceinline__ float b2f(unsigned short h) {
  return __uint_as_float(((unsigned)h) << 16);
}
__device__ __forceinline__ unsigned pk2f(float a, float b) {
  union { __hip_bfloat162 h; unsigned u; } cv;
  cv.h = __float22bfloat162_rn(make_float2(a, b));
  return cv.u;
}
__device__ __forceinline__ bf16x8 cvt8(float4 a, float4 b) {
  union { bf16x8 v; unsigned u[4]; } r;
  r.u[0]=pk2f(a.x,a.y); r.u[1]=pk2f(a.z,a.w);
  r.u[2]=pk2f(b.x,b.y); r.u[3]=pk2f(b.z,b.w);
  return r.v;
}
__device__ __forceinline__ float sumsq4(float4 a){ return a.x*a.x+a.y*a.y+a.z*a.z+a.w*a.w; }
__device__ __forceinline__ float4 sc4(float4 f){ return make_float4(NRM_*f.x,NRM_*f.y,NRM_*f.z,NRM_*f.w); }

// K1: blocks 0..511 -> k chunk-max (blockmax[blk]); 512..1023 -> q-features,
// written in A-fragment-packed layout qpP[ch][w 4][kk 8][m16 16][q4 4][e 8].
__global__ __launch_bounds__(256, 2) void feat_all(
    const float* __restrict__ qg, const float* __restrict__ kg,
    const float* __restrict__ projg,
    unsigned short* __restrict__ qpP, float* __restrict__ blockmax)
{
  __shared__ unsigned short R0[256*72];   // proj bf16 [m][d]; q-blocks overlay qS [64][264]
  __shared__ float xS[64*68];
  __shared__ float rmS[4][64];
  const int t=threadIdx.x, bb=blockIdx.x;
  const bool isq = bb >= NCH_;
  const int blk = bb & (NCH_-1);
  const float* x = isq ? qg : kg;
  const int row0 = blk*64;
  const int lane=t&63, m16=lane&15, q4=lane>>4, w=t>>6;
  const int f0 = w*64;

#pragma unroll
  for (int i=0;i<8;++i){ int flat=i*2048+t*8; int f=flat>>6, d2=flat&63;
    float4 p0 = *(const float4*)(projg+flat);
    float4 p1 = *(const float4*)(projg+flat+4);
    *(uint4*)&R0[f*72+d2] = make_uint4(pk2f(p0.x,p0.y),pk2f(p0.z,p0.w),
                                       pk2f(p1.x,p1.y),pk2f(p1.z,p1.w)); }
  const float* xg = x + (size_t)row0*64;
#pragma unroll
  for (int i=0;i<4;++i){ int flat=i*1024+t*4; int r=flat>>6, d2=flat&63;
    *(float4*)&xS[r*68+d2] = *(const float4*)(xg+flat); }
  __syncthreads();

  bf16x8 b[4][2]; float diag4[4];
#pragma unroll
  for (int rt=0;rt<4;++rt){
    const float* xr = &xS[(rt*16+m16)*68 + q4*8];
    float4 x0=*(const float4*)(xr), x1=*(const float4*)(xr+4);
    float4 x2=*(const float4*)(xr+32), x3=*(const float4*)(xr+36);
    float sq = sumsq4(x0)+sumsq4(x1)+sumsq4(x2)+sumsq4(x3);
    sq += __shfl_xor(sq,16); sq += __shfl_xor(sq,32);
    diag4[rt] = 0.0625f*sq;
    b[rt][0]=cvt8(sc4(x0),sc4(x1)); b[rt][1]=cvt8(sc4(x2),sc4(x3));
  }

  f32x4 acc[4][4];
#pragma unroll
  for (int rt=0;rt<4;++rt)
#pragma unroll
    for (int mt=0;mt<4;++mt) acc[rt][mt] = (f32x4){0.f,0.f,0.f,0.f};
#pragma unroll
  for (int kk=0;kk<2;++kk)
#pragma unroll
    for (int mt=0;mt<4;++mt){
      bf16x8 a = *(const bf16x8*)&R0[(f0+mt*16+m16)*72 + kk*32 + q4*8];
#pragma unroll
      for (int rt=0;rt<4;++rt)
        acc[rt][mt] = MFMA(a, b[rt][kk], acc[rt][mt]);
    }

  if (!isq) {
    float mx = acc[0][0][0];
#pragma unroll
    for (int rt=0;rt<4;++rt)
#pragma unroll
      for (int mt=0;mt<4;++mt)
#pragma unroll
        for (int j=0;j<4;++j) mx = fmaxf(mx, acc[rt][mt][j]);
#pragma unroll
    for (int off=1; off<64; off<<=1) mx = fmaxf(mx, __shfl_xor(mx, off));
    if (lane == 0) rmS[w][0] = mx;
    __syncthreads();
    if (t == 0)
      blockmax[blk] = fmaxf(fmaxf(rmS[0][0],rmS[1][0]),fmaxf(rmS[2][0],rmS[3][0]));
  } else {
    unsigned short* qS = R0;
#pragma unroll
    for (int rt=0;rt<4;++rt){
      float p = acc[rt][0][0];
#pragma unroll
      for (int mt=0;mt<4;++mt)
#pragma unroll
        for (int j=0;j<4;++j) p = fmaxf(p, acc[rt][mt][j]);
      p = fmaxf(p, __shfl_xor(p,16)); p = fmaxf(p, __shfl_xor(p,32));
      if (q4 == 0) rmS[w][rt*16+m16] = p;
    }
    __syncthreads();   // rmS ready; proj reads done -> overlay safe
#pragma unroll
    for (int rt=0;rt<4;++rt){
      int rr = rt*16+m16;
      float rm = fmaxf(fmaxf(rmS[0][rr],rmS[1][rr]),fmaxf(rmS[2][rr],rmS[3][rr]));
      float e = diag4[rt] + rm;
#pragma unroll
      for (int mt=0;mt<4;++mt){
        float v0 = RATIO_*(__expf(acc[rt][mt][0]-e)+1e-4f);
        float v1 = RATIO_*(__expf(acc[rt][mt][1]-e)+1e-4f);
        float v2 = RATIO_*(__expf(acc[rt][mt][2]-e)+1e-4f);
        float v3 = RATIO_*(__expf(acc[rt][mt][3]-e)+1e-4f);
        *(uint2*)&qS[rr*264 + f0 + mt*16 + q4*4] = make_uint2(pk2f(v0,v1), pk2f(v2,v3));
      }
    }
    __syncthreads();
    // packed store: b = (wp,kk,m16,q4) -> contiguous
#pragma unroll
    for (int i=0;i<8;++i){
      int bidx = i*256 + t;
      int wp = bidx>>9, m16p = (bidx>>2)&15, kkp = (bidx>>6)&7, q4p = bidx&3;
      *(uint4*)(qpP + (size_t)blk*16384 + bidx*8) =
          *(const uint4*)&qS[(wp*16+m16p)*264 + kkp*32 + q4p*8];
    }
  }
}

// K2: recompute k xd, exp -> kp (row-major) ; chunk-sum GEMM via kpT/vextS LDS
// -> kvxP packed [ch][ct 5][mtile 16][m16 16][c16 16], coalesced stores.
__global__ __launch_bounds__(256, 2) void kexp_kernel(
    const float* __restrict__ kg, const float* __restrict__ vg,
    const float* __restrict__ projg, const float* __restrict__ blockmax,
    unsigned short* __restrict__ kp, unsigned short* __restrict__ kvxP)
{
  __shared__ unsigned short A_[256*72];   // projS -> overlay kpS [64][264]
  __shared__ float B_f[64*72];            // xS -> overlay kpT [128][72] u16
  __shared__ unsigned short C_[80*72];    // vextS [c][s]
  __shared__ float kmS;
  const int t=threadIdx.x, ch=blockIdx.x;
  const int row0 = ch*64;
  const int lane=t&63, m16=lane&15, q4=lane>>4, w=t>>6;
  const int f0 = w*64;
  unsigned short* kpS = A_;
  unsigned short* kpT = (unsigned short*)B_f;

#pragma unroll
  for (int i=0;i<8;++i){ int flat=i*2048+t*8; int f=flat>>6, d2=flat&63;
    float4 p0 = *(const float4*)(projg+flat);
    float4 p1 = *(const float4*)(projg+flat+4);
    *(uint4*)&A_[f*72+d2] = make_uint4(pk2f(p0.x,p0.y),pk2f(p0.z,p0.w),
                                       pk2f(p1.x,p1.y),pk2f(p1.z,p1.w)); }
  const float* xg = kg + (size_t)row0*64;
#pragma unroll
  for (int i=0;i<4;++i){ int flat=i*1024+t*4; int r=flat>>6, d2=flat&63;
    *(float4*)&B_f[r*72+d2] = *(const float4*)(xg+flat); }
  {  // vextS: coalesced v loads, strided u16 LDS writes
    int c = t&63, sq = t>>6;
#pragma unroll
    for (int i=0;i<16;++i)
      C_[c*72 + sq*16 + i] = f2b(vg[((size_t)row0 + sq*16 + i)*64 + c]);
    int cc = 64 + (t>>4), s4 = (t&15)*4;
    unsigned short hv = (cc==64) ? (unsigned short)0x3F80 : (unsigned short)0;
    unsigned pv = (unsigned)hv | ((unsigned)hv<<16);
    *(uint2*)&C_[cc*72 + s4] = make_uint2(pv, pv);
  }
  if (t < 32) {
    float bm = blockmax[(ch>>5)*32 + t];
#pragma unroll
    for (int off=16; off>=1; off>>=1) bm = fmaxf(bm, __shfl_xor(bm, off));
    if (t == 0) kmS = bm;
  }
  __syncthreads();

  bf16x8 b[4][2]; float diag4[4];
#pragma unroll
  for (int rt=0;rt<4;++rt){
    const float* xr = &B_f[(rt*16+m16)*72 + q4*8];
    float4 x0=*(const float4*)(xr), x1=*(const float4*)(xr+4);
    float4 x2=*(const float4*)(xr+32), x3=*(const float4*)(xr+36);
    float sq = sumsq4(x0)+sumsq4(x1)+sumsq4(x2)+sumsq4(x3);
    sq += __shfl_xor(sq,16); sq += __shfl_xor(sq,32);
    diag4[rt] = 0.0625f*sq;
    b[rt][0]=cvt8(sc4(x0),sc4(x1)); b[rt][1]=cvt8(sc4(x2),sc4(x3));
  }
  const float kmx = kmS;

  f32x4 acc[4][4];
#pragma unroll
  for (int rt=0;rt<4;++rt)
#pragma unroll
    for (int mt=0;mt<4;++mt) acc[rt][mt] = (f32x4){0.f,0.f,0.f,0.f};
#pragma unroll
  for (int kk=0;kk<2;++kk)
#pragma unroll
    for (int mt=0;mt<4;++mt){
      bf16x8 a = *(const bf16x8*)&A_[(f0+mt*16+m16)*72 + kk*32 + q4*8];
#pragma unroll
      for (int rt=0;rt<4;++rt)
        acc[rt][mt] = MFMA(a, b[rt][kk], acc[rt][mt]);
    }
  __syncthreads();   // all projS/xS reads done -> overlays safe

  unsigned kpx[4][4][2];
#pragma unroll
  for (int rt=0;rt<4;++rt){
    float e = diag4[rt] + kmx;
    int rr = rt*16+m16;
#pragma unroll
    for (int mt=0;mt<4;++mt){
      float v0 = RATIO_*(__expf(acc[rt][mt][0]-e)+1e-4f);
      float v1 = RATIO_*(__expf(acc[rt][mt][1]-e)+1e-4f);
      float v2 = RATIO_*(__expf(acc[rt][mt][2]-e)+1e-4f);
      float v3 = RATIO_*(__expf(acc[rt][mt][3]-e)+1e-4f);
      kpx[rt][mt][0] = pk2f(v0,v1); kpx[rt][mt][1] = pk2f(v2,v3);
      *(uint2*)&kpS[rr*264 + f0 + mt*16 + q4*4] = make_uint2(kpx[rt][mt][0], kpx[rt][mt][1]);
    }
  }
  // kpT half 0 (features 0..127 owned by waves 0,1)
  if ((w>>1) == 0) {
#pragma unroll
    for (int rt=0;rt<4;++rt)
#pragma unroll
      for (int mt=0;mt<4;++mt)
#pragma unroll
        for (int jp=0;jp<2;++jp){
          int frl = (w&1)*64 + mt*16 + q4*4 + jp*2;
          unsigned uv = kpx[rt][mt][jp];
          kpT[frl*72 + rt*16+m16]     = (unsigned short)uv;
          kpT[(frl+1)*72 + rt*16+m16] = (unsigned short)(uv>>16);
        }
  }
  __syncthreads();
  // kp global store (row-major, coalesced)
#pragma unroll
  for (int i=0;i<8;++i){ int flat=i*2048+t*8; int r=flat>>8, c2=flat&255;
    *(uint4*)(kp + (size_t)row0*256 + flat) = *(const uint4*)&kpS[r*264 + c2]; }

  f32x4 c2a[5][2];
#pragma unroll
  for (int h=0; h<2; ++h) {
    if (h == 1) {
      __syncthreads();
      if ((w>>1) == 1) {
#pragma unroll
        for (int rt=0;rt<4;++rt)
#pragma unroll
          for (int mt=0;mt<4;++mt)
#pragma unroll
            for (int jp=0;jp<2;++jp){
              int frl = (w&1)*64 + mt*16 + q4*4 + jp*2;
              unsigned uv = kpx[rt][mt][jp];
              kpT[frl*72 + rt*16+m16]     = (unsigned short)uv;
              kpT[(frl+1)*72 + rt*16+m16] = (unsigned short)(uv>>16);
            }
      }
      __syncthreads();
    }
#pragma unroll
    for (int ct=0;ct<5;++ct)
#pragma unroll
      for (int p=0;p<2;++p) c2a[ct][p] = (f32x4){0.f,0.f,0.f,0.f};
#pragma unroll
    for (int kk=0;kk<2;++kk){
      bf16x8 av[5];
#pragma unroll
      for (int ct=0;ct<5;++ct)
        av[ct] = *(const bf16x8*)&C_[(ct*16+m16)*72 + kk*32 + q4*8];
#pragma unroll
      for (int p=0;p<2;++p){
        int mtl = w*2 + p;   // local tile in half
        bf16x8 bv = *(const bf16x8*)&kpT[(mtl*16+m16)*72 + kk*32 + q4*8];
#pragma unroll
        for (int ct=0;ct<5;++ct)
          c2a[ct][p] = MFMA(av[ct], bv, c2a[ct][p]);
      }
    }
#pragma unroll
    for (int ct=0;ct<5;++ct)
#pragma unroll
      for (int p=0;p<2;++p){
        int mtg = h*8 + w*2 + p;
        size_t base = (((size_t)ch*5 + ct)*16 + mtg)*256 + m16*16 + q4*4;
        *(uint2*)(kvxP + base) = make_uint2(pk2f(c2a[ct][p][0],c2a[ct][p][1]),
                                            pk2f(c2a[ct][p][2],c2a[ct][p][3]));
      }
    if (h == 0) __syncthreads();  // h0 kpT reads done before h1 overwrite
  }
}

// K3: exclusive prefix over 32 chunks, one (bh,c) per block, thread = m.
// 32 independent loads -> register prefix -> coalesced stores. c==65 -> eps.
__global__ __launch_bounds__(256, 4) void scan_kernel(
    const unsigned short* __restrict__ kvxP, unsigned short* __restrict__ SxT)
{
  const int t = threadIdx.x;
  const int c = blockIdx.x % 80, bh = blockIdx.x / 80;
  const int ct = c>>4, c16 = c&15, mtile = t>>4, m16l = t&15;
  size_t lbase = ((((size_t)bh*32*5 + ct)*16 + mtile)*16 + m16l)*16 + c16;
  float vals[32];
#pragma unroll
  for (int chl=0; chl<32; ++chl)
    vals[chl] = b2f(kvxP[lbase + (size_t)chl*20480]);
  float carry = 0.f;
  const bool is65 = (c == 65);
#pragma unroll
  for (int chl=0; chl<32; ++chl){
    float sv = is65 ? 1e-6f : carry;
    SxT[((size_t)(bh*32+chl)*80 + c)*256 + t] = f2b(sv);
    carry += vals[chl];
  }
}

// K4: A = Q'K'^T (masked -> P) ; O = Q'*Sext + P*Vext ; den = O[:,64]+O[:,65].
// qp: packed direct loads. kp+Sx: LDS stride 268 (conflict-free). Vext built from v.
__global__ __launch_bounds__(256, 2) void out_kernel(
    const unsigned short* __restrict__ qpP, const unsigned short* __restrict__ kp,
    const unsigned short* __restrict__ SxT, const float* __restrict__ vg,
    float* __restrict__ out_g)
{
  __shared__ unsigned short ldsS[144*268];   // kpS [64][268] + SxS [80][268]
  unsigned short* P  = ldsS;                 // overlay phase2: [64][72]
  unsigned short* vx = ldsS + 64*72;         // overlay phase2: [80][72]
  float* oT = (float*)(ldsS + 16384);        // overlay epilogue: [64][68] fp32
  const int t=threadIdx.x, ch=blockIdx.x;
  const int row0 = ch*64;
  const int lane=t&63, m16=lane&15, q4=lane>>4, w=t>>6;
  const int r0 = w*16;

  float vreg[16];   // prefetch v for Vext
  {
    int c = t&63, sq = t>>6;
#pragma unroll
    for (int i=0;i<16;++i)
      vreg[i] = vg[((size_t)row0 + sq*16 + i)*64 + c];
  }
  {
    const unsigned short* ksrc = kp + (size_t)row0*256;
#pragma unroll
    for (int i=0;i<8;++i){ int flat=i*2048+t*8; int r=flat>>8, c2=flat&255;
      *(uint4*)&ldsS[r*268+c2] = *(const uint4*)(ksrc+flat); }
    const unsigned short* ssrc = SxT + (size_t)ch*80*256;
#pragma unroll
    for (int i=0;i<10;++i){ int flat=i*2048+t*8; int r=flat>>8, c2=flat&255;
      *(uint4*)&ldsS[(64+r)*268+c2] = *(const uint4*)(ssrc+flat); }
  }
  __syncthreads();

  f32x4 accA[4], accO[5];
#pragma unroll
  for (int i=0;i<4;++i) accA[i] = (f32x4){0.f,0.f,0.f,0.f};
#pragma unroll
  for (int i=0;i<5;++i) accO[i] = (f32x4){0.f,0.f,0.f,0.f};

  const unsigned short* qpw = qpP + (size_t)ch*16384 + w*4096 + m16*32 + q4*8;
#pragma unroll
  for (int kk=0;kk<8;++kk){
    bf16x8 a = *(const bf16x8*)(qpw + kk*512);
#pragma unroll
    for (int st=0;st<4;++st){
      bf16x8 bfr = *(const bf16x8*)&ldsS[(st*16+m16)*268 + kk*32 + q4*8];
      accA[st] = MFMA(a, bfr, accA[st]);
    }
#pragma unroll
    for (int ct=0;ct<5;++ct){
      bf16x8 bfr = *(const bf16x8*)&ldsS[(64+ct*16+m16)*268 + kk*32 + q4*8];
      accO[ct] = MFMA(a, bfr, accO[ct]);
    }
  }
  __syncthreads();   // phase-1 LDS reads done -> overlays safe

#pragma unroll
  for (int st=0;st<4;++st)
#pragma unroll
    for (int j=0;j<4;++j){
      int rr = r0 + q4*4 + j;
      int cc = st*16 + m16;
      P[rr*72 + cc] = f2b((cc<=rr) ? accA[st][j] : 0.f);
    }
  {
    int c = t&63, sq = t>>6;
#pragma unroll
    for (int i=0;i<16;++i)
      vx[c*72 + sq*16 + i] = f2b(vreg[i]);
    int cc = 64 + (t>>4), s4 = (t&15)*4;
    unsigned short hv = (cc==64) ? (unsigned short)0x3F80 : (unsigned short)0;
    unsigned pv = (unsigned)hv | ((unsigned)hv<<16);
    *(uint2*)&vx[cc*72 + s4] = make_uint2(pv, pv);
  }
  __syncthreads();

#pragma unroll
  for (int k2=0;k2<2;++k2){
    bf16x8 aP = *(const bf16x8*)&P[(r0+m16)*72 + k2*32 + q4*8];
#pragma unroll
    for (int ct=0;ct<5;++ct){
      bf16x8 bfr = *(const bf16x8*)&vx[(ct*16+m16)*72 + k2*32 + q4*8];
      accO[ct] = MFMA(aP, bfr, accO[ct]);
    }
  }
#pragma unroll
  for (int j=0;j<4;++j){
    float d64 = __shfl(accO[4][j], (lane & 48));
    float d65 = __shfl(accO[4][j], (lane & 48) | 1);
    float dinv = 1.f/(d64+d65);
    int rr = r0 + q4*4 + j;
#pragma unroll
    for (int ct=0;ct<4;++ct)
      oT[rr*68 + ct*16 + m16] = accO[ct][j]*dinv;
  }
  __syncthreads();
#pragma unroll
  for (int i=0;i<4;++i){ int flat=i*1024+t*4; int r=flat>>6, c2=flat&63;
    *(float4*)(out_g + (size_t)row0*64 + flat) = *(const float4*)&oT[r*68+c2]; }
}

extern "C" void kernel_launch(void* const* d_in, const int* in_sizes, int n_in,
                              void* d_out, int out_size, void* d_ws, size_t ws_size,
                              hipStream_t stream)
{
  (void)in_sizes; (void)n_in; (void)out_size; (void)ws_size;
  const float* q    = (const float*)d_in[0];
  const float* k    = (const float*)d_in[1];
  const float* v    = (const float*)d_in[2];
  const float* proj = (const float*)d_in[3];
  float* out = (float*)d_out;

  char* p8 = (char*)d_ws;
  unsigned short* qpP  = (unsigned short*)p8; p8 += (size_t)NROW_*256*2;    // 16.78 MB
  unsigned short* kp   = (unsigned short*)p8; p8 += (size_t)NROW_*256*2;    // 16.78 MB
  unsigned short* kvxP = (unsigned short*)p8; p8 += (size_t)NCH_*80*256*2;  // 20.97 MB
  unsigned short* SxT  = (unsigned short*)p8; p8 += (size_t)NCH_*80*256*2;  // 20.97 MB
  float* blockmax = (float*)p8;

  feat_all   <<<dim3(2*NCH_), dim3(256), 0, stream>>>(q, k, proj, qpP, blockmax);
  kexp_kernel<<<dim3(NCH_),   dim3(256), 0, stream>>>(k, v, proj, blockmax, kp, kvxP);
  scan_kernel<<<dim3(BH_*80), dim3(256), 0, stream>>>(kvxP, SxT);
  out_kernel <<<dim3(NCH_),   dim3(256), 0, stream>>>(qpP, kp, SxT, v, out);
}